// Round 12
// baseline (352.552 us; speedup 1.0000x reference)
//
#include <hip/hip_runtime.h>
#include <hip/hip_bf16.h>
#include <math.h>

// Problem constants
#define B 32
#define T 64
#define P 196
#define D 768
#define H 12

typedef __attribute__((ext_vector_type(8))) short short8;
typedef __attribute__((ext_vector_type(4))) float floatx4;

// ---------------- helpers ----------------
__device__ __forceinline__ float wave_sum(float v) {
#pragma unroll
  for (int o = 32; o > 0; o >>= 1) v += __shfl_xor(v, o);
  return v;
}
__device__ __forceinline__ float wave_max(float v) {
#pragma unroll
  for (int o = 32; o > 0; o >>= 1) v = fmaxf(v, __shfl_xor(v, o));
  return v;
}
__device__ __forceinline__ unsigned short f2bf(float x) {
  unsigned u = __float_as_uint(x);
  u += 0x7FFFu + ((u >> 16) & 1u);   // round-to-nearest-even
  return (unsigned short)(u >> 16);
}

// ---------------- cast kernels ----------------
__global__ __launch_bounds__(256) void cast_rows2(
    const float* __restrict__ X0, unsigned short* __restrict__ Y0, int n40,
    const float* __restrict__ X1, unsigned short* __restrict__ Y1, int n41) {
  int i = blockIdx.x * 256 + threadIdx.x;
  const float* X;
  unsigned short* Y;
  int idx;
  if (i < n40) { X = X0; Y = Y0; idx = i; }
  else if (i < n40 + n41) { X = X1; Y = Y1; idx = i - n40; }
  else return;
  float4 vv = ((const float4*)X)[idx];
  ushort4 o;
  o.x = f2bf(vv.x); o.y = f2bf(vv.y); o.z = f2bf(vv.z); o.w = f2bf(vv.w);
  ((ushort4*)Y)[idx] = o;
}

// 6 weights fp32 [K][N] -> bf16 [N][K], one fused launch (grid.z = weight idx)
struct WPack {
  const float* src[6];
  unsigned short* dst[6];
};
__global__ __launch_bounds__(256) void cast_transpose6(WPack p, int K, int N) {
  __shared__ float tile[32][33];
  const float* W = p.src[blockIdx.z];
  unsigned short* Wt = p.dst[blockIdx.z];
  const int tx = threadIdx.x & 31, ty = threadIdx.x >> 5;  // ty 0..7
  const int n0 = blockIdx.x * 32, k0 = blockIdx.y * 32;
#pragma unroll
  for (int r = 0; r < 4; ++r)
    tile[ty + 8 * r][tx] = W[(size_t)(k0 + ty + 8 * r) * N + n0 + tx];
  __syncthreads();
#pragma unroll
  for (int r = 0; r < 4; ++r)
    Wt[(size_t)(n0 + ty + 8 * r) * K + k0 + tx] = f2bf(tile[tx][ty + 8 * r]);
}

// biases: bt = [bq, 0] (1536), bi = [bk, bv, 0] (2304); also zero s_token
__global__ __launch_bounds__(256) void build_bias(const float* __restrict__ bq,
                                                  const float* __restrict__ bk,
                                                  const float* __restrict__ bv,
                                                  float* __restrict__ bt,
                                                  float* __restrict__ bi,
                                                  float* __restrict__ stok) {
  int i = blockIdx.x * 256 + threadIdx.x;
  if (i < 32) stok[i] = 0.f;
  if (i < 768) { bt[i] = bq[i]; bi[i] = bk[i]; }
  else if (i < 1536) { bt[i] = 0.f; bi[i] = bv[i - 768]; }
  else if (i < 2304) { bi[i] = 0.f; }
}

// ---------------- bf16 MFMA GEMM body (software-pipelined) ----------------
struct GemmJob {
  const unsigned short* A;   // [M][K] bf16
  const unsigned short* Bt;  // [N][K] bf16
  const float* bias;
  float* C;
  int N, K, colTiles;
};

__device__ __forceinline__ void gemm_body(const GemmJob& j, int bx, int by, int tid) {
  __shared__ unsigned short As[128][40];
  __shared__ unsigned short Bs[128][40];
  const int lane = tid & 63;
  const int w = tid >> 6;
  const int quad = lane >> 4;
  const int l15 = lane & 15;
  const int row0 = by * 128;
  const int col0 = bx * 128;
  const int m_off = (w & 1) * 64;
  const int n_off = (w >> 1) * 64;
  const int lr = tid >> 2;
  const int lc = (tid & 3) * 8;
  const int N = j.N, K = j.K;

  const unsigned short* Ap0 = j.A + (size_t)(row0 + lr) * K + lc;
  const unsigned short* Ap1 = j.A + (size_t)(row0 + lr + 64) * K + lc;
  const unsigned short* Bp0 = j.Bt + (size_t)(col0 + lr) * K + lc;
  const unsigned short* Bp1 = j.Bt + (size_t)(col0 + lr + 64) * K + lc;

  floatx4 acc[4][4] = {};

  // prefetch k-tile 0
  uint4 a0 = *(const uint4*)Ap0;
  uint4 a1 = *(const uint4*)Ap1;
  uint4 b0 = *(const uint4*)Bp0;
  uint4 b1 = *(const uint4*)Bp1;

  for (int k0 = 0; k0 < K; k0 += 32) {
    __syncthreads();  // previous iteration's LDS reads complete
    *(uint4*)&As[lr][lc] = a0;
    *(uint4*)&As[lr + 64][lc] = a1;
    *(uint4*)&Bs[lr][lc] = b0;
    *(uint4*)&Bs[lr + 64][lc] = b1;
    __syncthreads();

    // issue next tile's loads (latency hidden under this tile's MFMAs);
    // last iteration harmlessly re-fetches tile 0 (L2-hot)
    const int kn = (k0 + 32 < K) ? (k0 + 32) : 0;
    a0 = *(const uint4*)(Ap0 + kn);
    a1 = *(const uint4*)(Ap1 + kn);
    b0 = *(const uint4*)(Bp0 + kn);
    b1 = *(const uint4*)(Bp1 + kn);

    short8 af[4], bfr[4];
#pragma unroll
    for (int i = 0; i < 4; ++i)
      af[i] = *(const short8*)&As[m_off + 16 * i + l15][quad * 8];
#pragma unroll
    for (int jj = 0; jj < 4; ++jj)
      bfr[jj] = *(const short8*)&Bs[n_off + 16 * jj + l15][quad * 8];
#pragma unroll
    for (int i = 0; i < 4; ++i)
#pragma unroll
      for (int jj = 0; jj < 4; ++jj)
        acc[i][jj] = __builtin_amdgcn_mfma_f32_16x16x32_bf16(af[i], bfr[jj], acc[i][jj], 0, 0, 0);
  }

#pragma unroll
  for (int jj = 0; jj < 4; ++jj) {
    const int cg = col0 + n_off + 16 * jj + l15;
    const float bv = j.bias ? j.bias[cg] : 0.0f;
#pragma unroll
    for (int i = 0; i < 4; ++i) {
      const int rbase = row0 + m_off + 16 * i + quad * 4;
#pragma unroll
      for (int r = 0; r < 4; ++r)
        j.C[(size_t)(rbase + r) * N + cg] = acc[i][jj][r] + bv;
    }
  }
}

__global__ __launch_bounds__(256) void gemm_mfma(GemmJob j) {
  gemm_body(j, blockIdx.x, blockIdx.y, threadIdx.x);
}

// two independent GEMMs in one launch; blockIdx.x < split -> job0 else job1
__global__ __launch_bounds__(256) void gemm_mfma_dual(GemmJob j0, GemmJob j1, int split) {
  const bool first = ((int)blockIdx.x < split);
  const GemmJob& j = first ? j0 : j1;
  const int bid = first ? blockIdx.x : (blockIdx.x - split);
  const int bx = bid % j.colTiles;
  const int by = bid / j.colTiles;
  gemm_body(j, bx, by, threadIdx.x);
}

// ---------------- MFMA cross attention: one block per (b,h), 4 waves ----------------
// qa: [B*T][1536] fp32 (q cols 0..767). kvw: [B*P][2304] fp32 (k 0..767, v 768..1535).
__global__ __launch_bounds__(256) void attn_mfma(
    const float* __restrict__ qa, const float* __restrict__ kvw,
    unsigned short* __restrict__ attout) {
  const int h = blockIdx.x, b = blockIdx.y;
  const int tid = threadIdx.x, lane = tid & 63, w = tid >> 6;
  const int quad = lane >> 4, l15 = lane & 15;

  __shared__ unsigned short Ks[196][72];     // K[p][d] bf16
  __shared__ unsigned short VT[64][232];     // V^T: VT[d][p]
  __shared__ unsigned short Ps[4][16][232];  // per-wave P (A-layout rows t_local)

  for (int i = tid; i < P * 64; i += 256) {
    const int p = i >> 6, d = i & 63;
    const float* row = kvw + (size_t)(b * P + p) * 2304 + h * 64 + d;
    Ks[p][d] = f2bf(row[0]);
    VT[d][p] = f2bf(row[768]);
  }
  if (tid < 64) {
    for (int c = 196; c < 224; ++c) VT[tid][c] = 0;
  }
  __syncthreads();

  short8 aq[2];
  {
    const float* qrow = qa + (size_t)(b * T + 16 * w + l15) * 1536 + h * 64;
#pragma unroll
    for (int ks = 0; ks < 2; ++ks) {
      const float4 x = *(const float4*)(qrow + 32 * ks + quad * 8);
      const float4 y = *(const float4*)(qrow + 32 * ks + quad * 8 + 4);
      short8 f;
      f[0] = (short)f2bf(x.x); f[1] = (short)f2bf(x.y);
      f[2] = (short)f2bf(x.z); f[3] = (short)f2bf(x.w);
      f[4] = (short)f2bf(y.x); f[5] = (short)f2bf(y.y);
      f[6] = (short)f2bf(y.z); f[7] = (short)f2bf(y.w);
      aq[ks] = f;
    }
  }

  floatx4 sc[13];
#pragma unroll
  for (int tile = 0; tile < 13; ++tile) {
    int p = tile * 16 + l15;
    if (p > 195) p = 195;
    short8 bk0 = *(const short8*)&Ks[p][quad * 8];
    short8 bk1 = *(const short8*)&Ks[p][32 + quad * 8];
    floatx4 c = {};
    c = __builtin_amdgcn_mfma_f32_16x16x32_bf16(aq[0], bk0, c, 0, 0, 0);
    c = __builtin_amdgcn_mfma_f32_16x16x32_bf16(aq[1], bk1, c, 0, 0, 0);
    sc[tile] = c;
  }

  float mx[4] = {-3.4e38f, -3.4e38f, -3.4e38f, -3.4e38f};
#pragma unroll
  for (int tile = 0; tile < 13; ++tile)
#pragma unroll
    for (int r = 0; r < 4; ++r) {
      float s = sc[tile][r] * 0.125f;
      if (tile == 12 && l15 >= 4) s = -3.0e38f;
      sc[tile][r] = s;
      mx[r] = fmaxf(mx[r], s);
    }
#pragma unroll
  for (int off = 1; off < 16; off <<= 1)
#pragma unroll
    for (int r = 0; r < 4; ++r) mx[r] = fmaxf(mx[r], __shfl_xor(mx[r], off));

  float sm[4] = {};
#pragma unroll
  for (int tile = 0; tile < 13; ++tile)
#pragma unroll
    for (int r = 0; r < 4; ++r) {
      float e = expf(sc[tile][r] - mx[r]);
      sc[tile][r] = e;
      sm[r] += e;
    }
#pragma unroll
  for (int off = 1; off < 16; off <<= 1)
#pragma unroll
    for (int r = 0; r < 4; ++r) sm[r] += __shfl_xor(sm[r], off);
  float inv[4];
#pragma unroll
  for (int r = 0; r < 4; ++r) inv[r] = 1.0f / sm[r];

#pragma unroll
  for (int tile = 0; tile < 13; ++tile)
#pragma unroll
    for (int r = 0; r < 4; ++r)
      Ps[w][quad * 4 + r][tile * 16 + l15] = f2bf(sc[tile][r] * inv[r]);
#pragma unroll
  for (int r = 0; r < 4; ++r)
    Ps[w][quad * 4 + r][208 + l15] = 0;

  __syncthreads();

  floatx4 oc[4] = {};
#pragma unroll
  for (int ks = 0; ks < 7; ++ks) {
    short8 pa = *(const short8*)&Ps[w][l15][ks * 32 + quad * 8];
#pragma unroll
    for (int nt = 0; nt < 4; ++nt) {
      short8 bv = *(const short8*)&VT[nt * 16 + l15][ks * 32 + quad * 8];
      oc[nt] = __builtin_amdgcn_mfma_f32_16x16x32_bf16(pa, bv, oc[nt], 0, 0, 0);
    }
  }

#pragma unroll
  for (int nt = 0; nt < 4; ++nt)
#pragma unroll
    for (int r = 0; r < 4; ++r)
      attout[(size_t)(b * T + 16 * w + quad * 4 + r) * 768 + h * 64 + nt * 16 + l15] =
          f2bf(oc[nt][r]);
}

// ---------------- token: grid (12, B). f_token slice + s_token partial ----------------
__global__ __launch_bounds__(256) void token_kernel(
    const float* __restrict__ upd, const float* __restrict__ img,
    float* __restrict__ f_token, float* __restrict__ s_token) {
  const int jt = blockIdx.x, b = blockIdx.y;
  const int l = threadIdx.x & 63, tg = threadIdx.x >> 6;
  const int d = jt * 64 + l;
  float fs = 0.f, ss = 0.f;
#pragma unroll 4
  for (int tt = 0; tt < 16; ++tt) {
    const int t = tg * 16 + tt;
    const float u = upd[(size_t)(b * T + t) * D + d];
    fs += u;
    ss += u * img[(size_t)(b * P + t) * D + d];
  }
  __shared__ float red[4][64];
  __shared__ float sred[4];
  red[tg][l] = fs;
  const float sw = wave_sum(ss);
  if (l == 0) sred[tg] = sw;
  __syncthreads();
  if (tg == 0) {
    f_token[(size_t)b * D + d] =
        (red[0][l] + red[1][l] + red[2][l] + red[3][l]) * (1.0f / T);
    if (threadIdx.x == 0)
      atomicAdd(&s_token[b], (sred[0] + sred[1] + sred[2] + sred[3]) * (1.0f / T));
  }
}

// ---------------- text GAT via MFMA: one block (4 waves) per (b,h). N=64 ----------------
__global__ __launch_bounds__(256) void text_gat_mfma(
    const float* __restrict__ Wh, int ldw, const int* __restrict__ adj,
    const float* __restrict__ at, float* __restrict__ tgf) {
  const int h = blockIdx.x, b = blockIdx.y;
  const int tid = threadIdx.x, lane = tid & 63, w = tid >> 6;
  const int quad = lane >> 4, l15 = lane & 15;

  __shared__ unsigned short VT[64][72];    // Wh^T bf16: VT[f][n]
  __shared__ unsigned short Ps[4][16][72]; // per-wave normalized att rows (A-layout)
  __shared__ float srcs[64], dsts[64];
  __shared__ float redc[4][64];
  __shared__ float asv[64], adv[64];

  if (tid < 64) { asv[tid] = at[tid]; adv[tid] = at[64 + tid]; }
  for (int i = tid; i < 64 * 64; i += 256) {
    const int n = i >> 6, f = i & 63;
    VT[f][n] = f2bf(Wh[(size_t)(b * T + n) * ldw + h * 64 + f]);
  }
  __syncthreads();

  if (tid < 64) {
    float s = 0.f, dd = 0.f;
#pragma unroll 8
    for (int f = 0; f < 64; ++f) {
      const float wv = __uint_as_float((unsigned)VT[f][tid] << 16);
      s += wv * asv[f];
      dd += wv * adv[f];
    }
    srcs[tid] = s;
    dsts[tid] = dd;
  }
  __syncthreads();

  const int i = 16 * w + l15;
  const float si = srcs[i];
  const int* ar = adj + (size_t)b * T * T + i * 64;
  float sm = 0.f;
#pragma unroll 8
  for (int jj = 0; jj < 16; ++jj) {
    const int j = 4 * jj + quad;
    float e = si + dsts[j];
    e = (e >= 0.f) ? e : 0.2f * e;
    const float p = (ar[j] != 0) ? expf(e) : 0.f;
    sm += p;
    Ps[w][l15][j] = f2bf(p);
  }
  sm += __shfl_xor(sm, 16);
  sm += __shfl_xor(sm, 32);
  const float inv = 1.0f / sm;
#pragma unroll 8
  for (int jj = 0; jj < 16; ++jj) {
    const int j = 4 * jj + quad;
    Ps[w][l15][j] = f2bf(__uint_as_float((unsigned)Ps[w][l15][j] << 16) * inv);
  }

  floatx4 oc[4] = {};
#pragma unroll
  for (int ks = 0; ks < 2; ++ks) {
    const short8 pa = *(const short8*)&Ps[w][l15][ks * 32 + quad * 8];
#pragma unroll
    for (int nt = 0; nt < 4; ++nt) {
      const short8 bv = *(const short8*)&VT[nt * 16 + l15][ks * 32 + quad * 8];
      oc[nt] = __builtin_amdgcn_mfma_f32_16x16x32_bf16(pa, bv, oc[nt], 0, 0, 0);
    }
  }

  float accd[4] = {};
#pragma unroll
  for (int r = 0; r < 4; ++r)
#pragma unroll
    for (int nt = 0; nt < 4; ++nt) {
      const float hp = oc[nt][r];
      accd[nt] += (hp > 0.f) ? hp : (expf(hp) - 1.0f);
    }
#pragma unroll
  for (int nt = 0; nt < 4; ++nt) {
    accd[nt] += __shfl_xor(accd[nt], 16);
    accd[nt] += __shfl_xor(accd[nt], 32);
  }
  if (quad == 0) {
#pragma unroll
    for (int nt = 0; nt < 4; ++nt) redc[w][nt * 16 + l15] = accd[nt];
  }
  __syncthreads();
  if (w == 0) {
    const float tot = redc[0][lane] + redc[1][lane] + redc[2][lane] + redc[3][lane];
    tgf[b * D + h * 64 + lane] = tot * (1.0f / T);
  }
}

// ---------------- image GAT stage 1: src/dst per (node, head) ----------------
__global__ __launch_bounds__(256) void sd_kernel(
    const float* __restrict__ Wh, int ldw, const float* __restrict__ ai,
    float* __restrict__ sd) {
  const int task = blockIdx.x * 4 + (threadIdx.x >> 6);  // 0 .. 75263
  const int lane = threadIdx.x & 63;
  const int n = task / 12, h = task - n * 12;            // n in [0, 6272)
  const float v = Wh[(size_t)n * ldw + h * 64 + lane];
  float s = v * ai[lane];
  float dd = v * ai[64 + lane];
#pragma unroll
  for (int o = 32; o > 0; o >>= 1) {
    s += __shfl_xor(s, o);
    dd += __shfl_xor(dd, o);
  }
  if (lane == 0) {
    const int b = n / P, nn = n - b * P;
    float* base = sd + (size_t)(b * 12 + h) * 392 + nn;
    base[0] = s;
    base[196] = dd;
  }
}

// ---------------- image GAT stage 2: normalized exp-scores -> S (A-layout) ----------------
__global__ __launch_bounds__(256) void score_kernel(
    const float* __restrict__ sd, const int* __restrict__ adj,
    unsigned short* __restrict__ S) {
  const int w = threadIdx.x >> 6, lane = threadIdx.x & 63;
  const int i = blockIdx.x * 4 + w;            // 0..195
  const int h = blockIdx.y, b = blockIdx.z;
  const float* sdp = sd + (size_t)(b * 12 + h) * 392;
  const float si = sdp[i];
  const int* ar = adj + i * P;

  float p0 = 0.f, p1 = 0.f, p2 = 0.f, p3 = 0.f;
  {
    float e;
    e = si + sdp[196 + lane];        e = (e >= 0.f) ? e : 0.2f * e;
    if (ar[lane] != 0) p0 = expf(e);
    e = si + sdp[196 + lane + 64];   e = (e >= 0.f) ? e : 0.2f * e;
    if (ar[lane + 64] != 0) p1 = expf(e);
    e = si + sdp[196 + lane + 128];  e = (e >= 0.f) ? e : 0.2f * e;
    if (ar[lane + 128] != 0) p2 = expf(e);
    if (lane < 4) {
      e = si + sdp[196 + lane + 192]; e = (e >= 0.f) ? e : 0.2f * e;
      if (ar[lane + 192] != 0) p3 = expf(e);
    }
  }
  const float inv = 1.0f / wave_sum(p0 + p1 + p2 + p3);

  unsigned short* row = S + ((size_t)(b * 12 + h) * 196 + i) * 224;
  row[lane] = f2bf(p0 * inv);
  row[lane + 64] = f2bf(p1 * inv);
  row[lane + 128] = f2bf(p2 * inv);
  if (lane < 4) row[lane + 192] = f2bf(p3 * inv);
  else if (lane < 32) row[lane + 192] = 0;
}

// ---------------- image GAT stage 3: hp = S @ Wh via MFMA, elu, mean ----------------
__global__ __launch_bounds__(256) void image_gat_mfma(
    const float* __restrict__ Wh, int ldw, const unsigned short* __restrict__ S,
    float* __restrict__ igf) {
  const int h = blockIdx.x, b = blockIdx.y;
  const int tid = threadIdx.x, lane = tid & 63, w = tid >> 6;
  const int quad = lane >> 4, l15 = lane & 15;

  __shared__ unsigned short VT[64][232];   // Wh^T bf16: VT[f][n]
  __shared__ float redc[4][64];

  for (int i = tid; i < P * 64; i += 256) {
    const int n = i >> 6, f = i & 63;
    VT[f][n] = f2bf(Wh[(size_t)(b * P + n) * ldw + h * 64 + f]);
  }
  if (tid < 64)
    for (int c = 196; c < 224; ++c) VT[tid][c] = 0;
  __syncthreads();

  const unsigned short* Sbh = S + (size_t)(b * 12 + h) * 196 * 224;
  float accd[4] = {};

  for (int tile = w; tile < 13; tile += 4) {
    const unsigned short* Srow = Sbh + (size_t)(tile * 16 + l15) * 224;
    floatx4 oc[4] = {};
#pragma unroll
    for (int ks = 0; ks < 7; ++ks) {
      const short8 pa = *(const short8*)(Srow + ks * 32 + quad * 8);
#pragma unroll
      for (int nt = 0; nt < 4; ++nt) {
        const short8 bv = *(const short8*)&VT[nt * 16 + l15][ks * 32 + quad * 8];
        oc[nt] = __builtin_amdgcn_mfma_f32_16x16x32_bf16(pa, bv, oc[nt], 0, 0, 0);
      }
    }
#pragma unroll
    for (int r = 0; r < 4; ++r) {
      const int io = tile * 16 + quad * 4 + r;
      if (io < P) {
#pragma unroll
        for (int nt = 0; nt < 4; ++nt) {
          const float hp = oc[nt][r];
          accd[nt] += (hp > 0.f) ? hp : (expf(hp) - 1.0f);
        }
      }
    }
  }

#pragma unroll
  for (int nt = 0; nt < 4; ++nt) {
    accd[nt] += __shfl_xor(accd[nt], 16);
    accd[nt] += __shfl_xor(accd[nt], 32);
  }
  if (quad == 0) {
#pragma unroll
    for (int nt = 0; nt < 4; ++nt) redc[w][nt * 16 + l15] = accd[nt];
  }
  __syncthreads();
  if (w == 0) {
    const float tot = redc[0][lane] + redc[1][lane] + redc[2][lane] + redc[3][lane];
    igf[b * D + h * 64 + lane] = tot * (1.0f / P);
  }
}

// ---------------- f_global = clip_t @ Wp + bp : grid (12, B) ----------------
__global__ __launch_bounds__(256) void fglob_kernel(
    const float* __restrict__ clip_t, const float* __restrict__ Wp,
    const float* __restrict__ bp, float* __restrict__ fglob) {
  const int jt = blockIdx.x, b = blockIdx.y;
  const int j = threadIdx.x & 63, kc = threadIdx.x >> 6;
  float s = 0.f;
  const float* ct = clip_t + b * 512;
#pragma unroll 4
  for (int k = kc * 128; k < kc * 128 + 128; ++k)
    s += ct[k] * Wp[(size_t)k * D + jt * 64 + j];
  __shared__ float red[4][64];
  red[kc][j] = s;
  __syncthreads();
  if (kc == 0)
    fglob[b * D + jt * 64 + j] = red[0][j] + red[1][j] + red[2][j] + red[3][j] + bp[jt * 64 + j];
}

// ---------------- Xc = [f_token; tgf; fglob] @ c1w : grid (6, 96) ----------------
__global__ __launch_bounds__(256) void xc1_kernel(
    const float* __restrict__ ftok, const float* __restrict__ tgf,
    const float* __restrict__ fglob, const float* __restrict__ c1w,
    float* __restrict__ Xc) {
  const int jt = blockIdx.x;
  const int r = blockIdx.y;
  const int b = r & 31, which = r >> 5;
  const float* src = (which == 0 ? ftok : which == 1 ? tgf : fglob) + (size_t)b * D;
  const int j = threadIdx.x & 63, kc = threadIdx.x >> 6;
  const int col = jt * 64 + j;
  float s = 0.f;
#pragma unroll 4
  for (int k = kc * 192; k < kc * 192 + 192; ++k)
    s += src[k] * c1w[(size_t)k * 384 + col];
  __shared__ float red[4][64];
  red[kc][j] = s;
  __syncthreads();
  if (kc == 0)
    Xc[(size_t)r * 384 + col] = red[0][j] + red[1][j] + red[2][j] + red[3][j];
}

// ---------------- final fusion kernel: one block per b ----------------
__device__ __forceinline__ float block_sum(float v, float* red4) {
  v = wave_sum(v);
  __syncthreads();
  if ((threadIdx.x & 63) == 0) red4[threadIdx.x >> 6] = v;
  __syncthreads();
  return red4[0] + red4[1] + red4[2] + red4[3];
}

__global__ __launch_bounds__(256) void final_kernel(
    const float* __restrict__ tgf, const float* __restrict__ igf,
    const float* __restrict__ clip_t, const float* __restrict__ clip_i,
    const float* __restrict__ logit_scale, const float* __restrict__ s_token,
    const float* __restrict__ Xc,
    const float* __restrict__ f1w, const float* __restrict__ f1b,
    const float* __restrict__ f2w, const float* __restrict__ f2b,
    const float* __restrict__ c1b,
    const float* __restrict__ c2w, const float* __restrict__ c2b,
    float* __restrict__ out) {
  const int b = blockIdx.x, tid = threadIdx.x;
  __shared__ float red[4];
  __shared__ float sres[4];
  __shared__ float hid[384];

  float d0 = 0.f, d1 = 0.f, d2 = 0.f;
  for (int i = tid; i < D; i += 256) {
    float x = tgf[b * D + i], y = igf[b * D + i];
    d0 += x * y; d1 += x * x; d2 += y * y;
  }
  float dot_ti = block_sum(d0, red);
  float n_t = sqrtf(block_sum(d1, red));
  float n_i = sqrtf(block_sum(d2, red));
  float s_phrase = dot_ti / (fmaxf(n_t, 1e-8f) * fmaxf(n_i, 1e-8f));

  float c0 = 0.f, c1 = 0.f, c2 = 0.f;
  for (int i = tid; i < 512; i += 256) {
    float x = clip_t[b * 512 + i], y = clip_i[b * 512 + i];
    c0 += x * y; c1 += x * x; c2 += y * y;
  }
  float dc = block_sum(c0, red);
  float nt2 = sqrtf(block_sum(c1, red));
  float ni2 = sqrtf(block_sum(c2, red));
  float s_global = expf(logit_scale[0]) * dc / (fmaxf(nt2, 1e-8f) * fmaxf(ni2, 1e-8f));

  if (tid == 0) {
    float s3[3] = { s_token[b], s_phrase, s_global };
    float h1[16];
    for (int j = 0; j < 16; ++j) {
      float a = f1b[j];
      for (int i2 = 0; i2 < 3; ++i2) a += s3[i2] * f1w[i2 * 16 + j];
      h1[j] = 0.5f * a * (1.0f + erff(a * 0.70710678118654752f));
    }
    for (int j = 0; j < 3; ++j) {
      float a = f2b[j];
      for (int i2 = 0; i2 < 16; ++i2) a += h1[i2] * f2w[i2 * 3 + j];
      sres[j] = 1.0f / (1.0f + expf(-a));
    }
  }
  __syncthreads();
  const float w0 = sres[0], w1 = sres[1], w2 = sres[2];

  for (int j = tid; j < 384; j += 256) {
    const float a = w0 * Xc[(size_t)b * 384 + j] +
                    w1 * Xc[(size_t)(32 + b) * 384 + j] +
                    w2 * Xc[(size_t)(64 + b) * 384 + j] + c1b[j];
    hid[j] = fmaxf(a, 0.0f);
  }
  __syncthreads();

  float p0 = 0.f, p1 = 0.f;
  for (int k2 = tid; k2 < 384; k2 += 256) {
    p0 += hid[k2] * c2w[k2 * 2 + 0];
    p1 += hid[k2] * c2w[k2 * 2 + 1];
  }
  p0 = block_sum(p0, red);
  p1 = block_sum(p1, red);
  if (tid == 0) {
    out[b * 2 + 0] = p0 + c2b[0];
    out[b * 2 + 1] = p1 + c2b[1];
  }
}

// ---------------- launch ----------------
extern "C" void kernel_launch(void* const* d_in, const int* in_sizes, int n_in,
                              void* d_out, int out_size, void* d_ws, size_t ws_size,
                              hipStream_t stream) {
  const float* text   = (const float*)d_in[0];
  const float* img    = (const float*)d_in[1];
  const float* clip_t = (const float*)d_in[2];
  const float* clip_i = (const float*)d_in[3];
  const float* lscale = (const float*)d_in[4];
  const float* wq = (const float*)d_in[5];
  const float* bq = (const float*)d_in[6];
  const float* wk = (const float*)d_in[7];
  const float* bk = (const float*)d_in[8];
  const float* wv = (const float*)d_in[9];
  const float* bv = (const float*)d_in[10];
  const float* wo = (const float*)d_in[11];
  const float* bo = (const float*)d_in[12];
  const float* Wt = (const float*)d_in[13];
  const float* at = (const float*)d_in[14];
  const float* Wi = (const float*)d_in[15];
  const float* ai = (const float*)d_in[16];
  const float* Wp = (const float*)d_in[17];
  const float* bp = (const float*)d_in[18];
  const float* f1w = (const float*)d_in[19];
  const float* f1b = (const float*)d_in[20];
  const float* f2w = (const float*)d_in[21];
  const float* f2b = (const float*)d_in[22];
  const float* c1w = (const float*)d_in[23];
  const float* c1b = (const float*)d_in[24];
  const float* c2w = (const float*)d_in[25];
  const float* c2b = (const float*)d_in[26];
  const int* text_adj  = (const int*)d_in[27];
  const int* image_adj = (const int*)d_in[28];
  float* out = (float*)d_out;

  const size_t nTD = (size_t)B * T * D;   // 1,572,864
  const size_t nPD = (size_t)B * P * D;   // 4,816,896
  const size_t nWW = (size_t)D * D;       // 589,824

  // ---- workspace layout (no aliasing; ~134 MB < 256 MiB ws) ----
  float* fbuf = (float*)d_ws;
  size_t o = 0;
  float* kvw_buf = fbuf + o; o += 3 * nPD;  // [B*P][2304]: k|v|Wh_i
  float* qa_buf  = fbuf + o; o += 2 * nTD;  // [B*T][1536]: q|Wh_t
  float* upd     = fbuf + o; o += nTD;
  float* ftok    = fbuf + o; o += (size_t)B * D;
  float* stok    = fbuf + o; o += 32;
  float* tgf     = fbuf + o; o += (size_t)B * D;
  float* igf     = fbuf + o; o += (size_t)B * D;
  float* fglob   = fbuf + o; o += (size_t)B * D;
  float* bcat_t  = fbuf + o; o += 1536;
  float* bcat_i3 = fbuf + o; o += 2304;
  float* sd      = fbuf + o; o += (size_t)384 * 392;
  float* Xc      = fbuf + o; o += (size_t)96 * 384;
  unsigned short* sbuf = (unsigned short*)(fbuf + o);
  size_t so = 0;
  unsigned short* text_bf   = sbuf + so; so += nTD;
  unsigned short* img_bf    = sbuf + so; so += nPD;
  unsigned short* att_bf    = sbuf + so; so += nTD;
  unsigned short* wcat_txt  = sbuf + so; so += 2 * nWW;  // wq^T | Wt^T
  unsigned short* wcat_img3 = sbuf + so; so += 3 * nWW;  // wk^T | wv^T | Wi^T
  unsigned short* wo_t      = sbuf + so; so += nWW;
  unsigned short* S         = sbuf + so; so += (size_t)384 * 196 * 224;

  // ---- weight casts + biases + activation casts ----
  WPack wp;
  wp.src[0] = wq; wp.dst[0] = wcat_txt;
  wp.src[1] = Wt; wp.dst[1] = wcat_txt + nWW;
  wp.src[2] = wk; wp.dst[2] = wcat_img3;
  wp.src[3] = wv; wp.dst[3] = wcat_img3 + nWW;
  wp.src[4] = Wi; wp.dst[4] = wcat_img3 + 2 * nWW;
  wp.src[5] = wo; wp.dst[5] = wo_t;
  cast_transpose6<<<dim3(D / 32, D / 32, 6), 256, 0, stream>>>(wp, D, D);
  build_bias<<<12, 256, 0, stream>>>(bq, bk, bv, bcat_t, bcat_i3, stok);
  {
    const int n40 = (int)(nTD / 4), n41 = (int)(nPD / 4);
    cast_rows2<<<(n40 + n41 + 255) / 256, 256, 0, stream>>>(text, text_bf, n40, img, img_bf, n41);
  }

  const int MT = B * T;   // 2048
  const int MP = B * P;   // 6272

  // ---- fused projections: one dual launch (img3: 882 blocks, text: 192 blocks) ----
  GemmJob jimg;  // kvw = img @ [wk|wv|Wi] + [bk,bv,0]
  jimg.A = img_bf; jimg.Bt = wcat_img3; jimg.bias = bcat_i3; jimg.C = kvw_buf;
  jimg.N = 2304; jimg.K = D; jimg.colTiles = 2304 / 128;            // 18 x 49
  GemmJob jtxt;  // qa = text @ [wq|Wt] + [bq,0]
  jtxt.A = text_bf; jtxt.Bt = wcat_txt; jtxt.bias = bcat_t; jtxt.C = qa_buf;
  jtxt.N = 1536; jtxt.K = D; jtxt.colTiles = 1536 / 128;            // 12 x 16
  const int splitBlocks = (2304 / 128) * (MP / 128);                // 882
  const int totalBlocks = splitBlocks + (1536 / 128) * (MT / 128);  // 882 + 192
  gemm_mfma_dual<<<totalBlocks, 256, 0, stream>>>(jimg, jtxt, splitBlocks);

  fglob_kernel<<<dim3(12, B), 256, 0, stream>>>(clip_t, Wp, bp, fglob);

  attn_mfma<<<dim3(H, B), 256, 0, stream>>>(qa_buf, kvw_buf, att_bf);

  GemmJob jwo;   // upd = att @ wo + bo
  jwo.A = att_bf; jwo.Bt = wo_t; jwo.bias = bo; jwo.C = upd;
  jwo.N = D; jwo.K = D; jwo.colTiles = D / 128;
  gemm_mfma<<<dim3(D / 128, MT / 128), 256, 0, stream>>>(jwo);

  token_kernel<<<dim3(12, B), 256, 0, stream>>>(upd, img, ftok, stok);
  text_gat_mfma<<<dim3(H, B), 256, 0, stream>>>(qa_buf + 768, 1536, text_adj, at, tgf);

  // ---- image GAT: 3-stage pipeline on whi = kvw cols 1536.. (stride 2304) ----
  const float* whi = kvw_buf + 1536;
  sd_kernel<<<MP * 12 / 4, 256, 0, stream>>>(whi, 2304, ai, sd);
  score_kernel<<<dim3(49, H, B), 256, 0, stream>>>(sd, image_adj, S);
  image_gat_mfma<<<dim3(H, B), 256, 0, stream>>>(whi, 2304, S, igf);

  xc1_kernel<<<dim3(6, 96), 256, 0, stream>>>(ftok, tgf, fglob, c1w, Xc);
  final_kernel<<<B, 256, 0, stream>>>(tgf, igf, clip_t, clip_i, lscale, stok, Xc,
                                      f1w, f1b, f2w, f2b, c1b, c2w, c2b, out);
}

// Round 13
// 351.790 us; speedup vs baseline: 1.0022x; 1.0022x over previous
//
#include <hip/hip_runtime.h>
#include <hip/hip_bf16.h>
#include <math.h>

// Problem constants
#define B 32
#define T 64
#define P 196
#define D 768
#define H 12

typedef __attribute__((ext_vector_type(8))) short short8;
typedef __attribute__((ext_vector_type(4))) float floatx4;

// ---------------- helpers ----------------
__device__ __forceinline__ float wave_sum(float v) {
#pragma unroll
  for (int o = 32; o > 0; o >>= 1) v += __shfl_xor(v, o);
  return v;
}
__device__ __forceinline__ float wave_max(float v) {
#pragma unroll
  for (int o = 32; o > 0; o >>= 1) v = fmaxf(v, __shfl_xor(v, o));
  return v;
}
__device__ __forceinline__ unsigned short f2bf(float x) {
  unsigned u = __float_as_uint(x);
  u += 0x7FFFu + ((u >> 16) & 1u);   // round-to-nearest-even
  return (unsigned short)(u >> 16);
}
// async global->LDS, 16B per lane; LDS dest = wave-uniform base + lane*16
__device__ __forceinline__ void async_cp16(const unsigned short* g, unsigned short* l) {
  __builtin_amdgcn_global_load_lds(
      (const __attribute__((address_space(1))) unsigned int*)g,
      (__attribute__((address_space(3))) unsigned int*)l, 16, 0, 0);
}

// ---------------- cast kernels ----------------
__global__ __launch_bounds__(256) void cast_rows2(
    const float* __restrict__ X0, unsigned short* __restrict__ Y0, int n40,
    const float* __restrict__ X1, unsigned short* __restrict__ Y1, int n41) {
  int i = blockIdx.x * 256 + threadIdx.x;
  const float* X;
  unsigned short* Y;
  int idx;
  if (i < n40) { X = X0; Y = Y0; idx = i; }
  else if (i < n40 + n41) { X = X1; Y = Y1; idx = i - n40; }
  else return;
  float4 vv = ((const float4*)X)[idx];
  ushort4 o;
  o.x = f2bf(vv.x); o.y = f2bf(vv.y); o.z = f2bf(vv.z); o.w = f2bf(vv.w);
  ((ushort4*)Y)[idx] = o;
}

// 6 weights fp32 [K][N] -> bf16 [N][K], one fused launch (grid.z = weight idx)
struct WPack {
  const float* src[6];
  unsigned short* dst[6];
};
__global__ __launch_bounds__(256) void cast_transpose6(WPack p, int K, int N) {
  __shared__ float tile[32][33];
  const float* W = p.src[blockIdx.z];
  unsigned short* Wt = p.dst[blockIdx.z];
  const int tx = threadIdx.x & 31, ty = threadIdx.x >> 5;  // ty 0..7
  const int n0 = blockIdx.x * 32, k0 = blockIdx.y * 32;
#pragma unroll
  for (int r = 0; r < 4; ++r)
    tile[ty + 8 * r][tx] = W[(size_t)(k0 + ty + 8 * r) * N + n0 + tx];
  __syncthreads();
#pragma unroll
  for (int r = 0; r < 4; ++r)
    Wt[(size_t)(n0 + ty + 8 * r) * K + k0 + tx] = f2bf(tile[tx][ty + 8 * r]);
}

// biases: bt = [bq, 0] (1536), bi = [bk, bv, 0] (2304); also zero s_token
__global__ __launch_bounds__(256) void build_bias(const float* __restrict__ bq,
                                                  const float* __restrict__ bk,
                                                  const float* __restrict__ bv,
                                                  float* __restrict__ bt,
                                                  float* __restrict__ bi,
                                                  float* __restrict__ stok) {
  int i = blockIdx.x * 256 + threadIdx.x;
  if (i < 32) stok[i] = 0.f;
  if (i < 768) { bt[i] = bq[i]; bi[i] = bk[i]; }
  else if (i < 1536) { bt[i] = 0.f; bi[i] = bv[i - 768]; }
  else if (i < 2304) { bi[i] = 0.f; }
}

// ---------------- bf16 MFMA GEMM body (global_load_lds staging, m97 structure) ----------------
struct GemmJob {
  const unsigned short* A;   // [M][K] bf16
  const unsigned short* Bt;  // [N][K] bf16
  const float* bias;
  float* C;
  int N, K, colTiles;
};

__device__ __forceinline__ void gemm_body(const GemmJob& j, int bx, int by, int tid) {
  __shared__ unsigned short As[128][32];  // unpadded: rows = 64 B (required by global_load_lds)
  __shared__ unsigned short Bs[128][32];
  const int lane = tid & 63;
  const int w = tid >> 6;
  const int quad = lane >> 4;
  const int l15 = lane & 15;
  const int row0 = by * 128;
  const int col0 = bx * 128;
  const int m_off = (w & 1) * 64;
  const int n_off = (w >> 1) * 64;
  const int N = j.N, K = j.K;

  // staging: wave w fills rows [16w,16w+16) and [64+16w, 64+16w+16) of As and Bs.
  // lane i covers row srow=16w+(i>>2), col (i&3)*8 — matches LDS dest base+lane*16.
  const int srow = 16 * w + (lane >> 2);
  const int scol = (lane & 3) * 8;
  const unsigned short* gA0 = j.A + (size_t)(row0 + srow) * K + scol;
  const unsigned short* gA1 = j.A + (size_t)(row0 + srow + 64) * K + scol;
  const unsigned short* gB0 = j.Bt + (size_t)(col0 + srow) * K + scol;
  const unsigned short* gB1 = j.Bt + (size_t)(col0 + srow + 64) * K + scol;
  unsigned short* lA0 = &As[16 * w][0];
  unsigned short* lA1 = &As[64 + 16 * w][0];
  unsigned short* lB0 = &Bs[16 * w][0];
  unsigned short* lB1 = &Bs[64 + 16 * w][0];

  floatx4 acc[4][4] = {};

  for (int k0 = 0; k0 < K; k0 += 32) {
    __syncthreads();  // previous iteration's fragment reads complete
    async_cp16(gA0 + k0, lA0);
    async_cp16(gA1 + k0, lA1);
    async_cp16(gB0 + k0, lB0);
    async_cp16(gB1 + k0, lB1);
    __syncthreads();  // drains vmcnt: staged data visible

    short8 af[4], bfr[4];
#pragma unroll
    for (int i = 0; i < 4; ++i)
      af[i] = *(const short8*)&As[m_off + 16 * i + l15][quad * 8];
#pragma unroll
    for (int jj = 0; jj < 4; ++jj)
      bfr[jj] = *(const short8*)&Bs[n_off + 16 * jj + l15][quad * 8];
#pragma unroll
    for (int i = 0; i < 4; ++i)
#pragma unroll
      for (int jj = 0; jj < 4; ++jj)
        acc[i][jj] = __builtin_amdgcn_mfma_f32_16x16x32_bf16(af[i], bfr[jj], acc[i][jj], 0, 0, 0);
  }

#pragma unroll
  for (int jj = 0; jj < 4; ++jj) {
    const int cg = col0 + n_off + 16 * jj + l15;
    const float bv = j.bias ? j.bias[cg] : 0.0f;
#pragma unroll
    for (int i = 0; i < 4; ++i) {
      const int rbase = row0 + m_off + 16 * i + quad * 4;
#pragma unroll
      for (int r = 0; r < 4; ++r)
        j.C[(size_t)(rbase + r) * N + cg] = acc[i][jj][r] + bv;
    }
  }
}

__global__ __launch_bounds__(256) void gemm_mfma(GemmJob j) {
  gemm_body(j, blockIdx.x, blockIdx.y, threadIdx.x);
}

// two independent GEMMs in one launch; blockIdx.x < split -> job0 else job1
__global__ __launch_bounds__(256) void gemm_mfma_dual(GemmJob j0, GemmJob j1, int split) {
  const bool first = ((int)blockIdx.x < split);
  const GemmJob& j = first ? j0 : j1;
  const int bid = first ? blockIdx.x : (blockIdx.x - split);
  const int bx = bid % j.colTiles;
  const int by = bid / j.colTiles;
  gemm_body(j, bx, by, threadIdx.x);
}

// ---------------- MFMA cross attention: one block per (b,h), 4 waves ----------------
// qa: [B*T][1536] fp32 (q cols 0..767). kvw: [B*P][2304] fp32 (k 0..767, v 768..1535).
__global__ __launch_bounds__(256) void attn_mfma(
    const float* __restrict__ qa, const float* __restrict__ kvw,
    unsigned short* __restrict__ attout) {
  const int h = blockIdx.x, b = blockIdx.y;
  const int tid = threadIdx.x, lane = tid & 63, w = tid >> 6;
  const int quad = lane >> 4, l15 = lane & 15;

  __shared__ unsigned short Ks[196][72];     // K[p][d] bf16
  __shared__ unsigned short VT[64][232];     // V^T: VT[d][p]
  __shared__ unsigned short Ps[4][16][232];  // per-wave P (A-layout rows t_local)

  for (int i = tid; i < P * 64; i += 256) {
    const int p = i >> 6, d = i & 63;
    const float* row = kvw + (size_t)(b * P + p) * 2304 + h * 64 + d;
    Ks[p][d] = f2bf(row[0]);
    VT[d][p] = f2bf(row[768]);
  }
  if (tid < 64) {
    for (int c = 196; c < 224; ++c) VT[tid][c] = 0;
  }
  __syncthreads();

  short8 aq[2];
  {
    const float* qrow = qa + (size_t)(b * T + 16 * w + l15) * 1536 + h * 64;
#pragma unroll
    for (int ks = 0; ks < 2; ++ks) {
      const float4 x = *(const float4*)(qrow + 32 * ks + quad * 8);
      const float4 y = *(const float4*)(qrow + 32 * ks + quad * 8 + 4);
      short8 f;
      f[0] = (short)f2bf(x.x); f[1] = (short)f2bf(x.y);
      f[2] = (short)f2bf(x.z); f[3] = (short)f2bf(x.w);
      f[4] = (short)f2bf(y.x); f[5] = (short)f2bf(y.y);
      f[6] = (short)f2bf(y.z); f[7] = (short)f2bf(y.w);
      aq[ks] = f;
    }
  }

  floatx4 sc[13];
#pragma unroll
  for (int tile = 0; tile < 13; ++tile) {
    int p = tile * 16 + l15;
    if (p > 195) p = 195;
    short8 bk0 = *(const short8*)&Ks[p][quad * 8];
    short8 bk1 = *(const short8*)&Ks[p][32 + quad * 8];
    floatx4 c = {};
    c = __builtin_amdgcn_mfma_f32_16x16x32_bf16(aq[0], bk0, c, 0, 0, 0);
    c = __builtin_amdgcn_mfma_f32_16x16x32_bf16(aq[1], bk1, c, 0, 0, 0);
    sc[tile] = c;
  }

  float mx[4] = {-3.4e38f, -3.4e38f, -3.4e38f, -3.4e38f};
#pragma unroll
  for (int tile = 0; tile < 13; ++tile)
#pragma unroll
    for (int r = 0; r < 4; ++r) {
      float s = sc[tile][r] * 0.125f;
      if (tile == 12 && l15 >= 4) s = -3.0e38f;
      sc[tile][r] = s;
      mx[r] = fmaxf(mx[r], s);
    }
#pragma unroll
  for (int off = 1; off < 16; off <<= 1)
#pragma unroll
    for (int r = 0; r < 4; ++r) mx[r] = fmaxf(mx[r], __shfl_xor(mx[r], off));

  float sm[4] = {};
#pragma unroll
  for (int tile = 0; tile < 13; ++tile)
#pragma unroll
    for (int r = 0; r < 4; ++r) {
      float e = expf(sc[tile][r] - mx[r]);
      sc[tile][r] = e;
      sm[r] += e;
    }
#pragma unroll
  for (int off = 1; off < 16; off <<= 1)
#pragma unroll
    for (int r = 0; r < 4; ++r) sm[r] += __shfl_xor(sm[r], off);
  float inv[4];
#pragma unroll
  for (int r = 0; r < 4; ++r) inv[r] = 1.0f / sm[r];

#pragma unroll
  for (int tile = 0; tile < 13; ++tile)
#pragma unroll
    for (int r = 0; r < 4; ++r)
      Ps[w][quad * 4 + r][tile * 16 + l15] = f2bf(sc[tile][r] * inv[r]);
#pragma unroll
  for (int r = 0; r < 4; ++r)
    Ps[w][quad * 4 + r][208 + l15] = 0;

  __syncthreads();

  floatx4 oc[4] = {};
#pragma unroll
  for (int ks = 0; ks < 7; ++ks) {
    short8 pa = *(const short8*)&Ps[w][l15][ks * 32 + quad * 8];
#pragma unroll
    for (int nt = 0; nt < 4; ++nt) {
      short8 bv = *(const short8*)&VT[nt * 16 + l15][ks * 32 + quad * 8];
      oc[nt] = __builtin_amdgcn_mfma_f32_16x16x32_bf16(pa, bv, oc[nt], 0, 0, 0);
    }
  }

#pragma unroll
  for (int nt = 0; nt < 4; ++nt)
#pragma unroll
    for (int r = 0; r < 4; ++r)
      attout[(size_t)(b * T + 16 * w + quad * 4 + r) * 768 + h * 64 + nt * 16 + l15] =
          f2bf(oc[nt][r]);
}

// ---------------- token: grid (12, B). f_token slice + s_token partial ----------------
__global__ __launch_bounds__(256) void token_kernel(
    const float* __restrict__ upd, const float* __restrict__ img,
    float* __restrict__ f_token, float* __restrict__ s_token) {
  const int jt = blockIdx.x, b = blockIdx.y;
  const int l = threadIdx.x & 63, tg = threadIdx.x >> 6;
  const int d = jt * 64 + l;
  float fs = 0.f, ss = 0.f;
#pragma unroll 4
  for (int tt = 0; tt < 16; ++tt) {
    const int t = tg * 16 + tt;
    const float u = upd[(size_t)(b * T + t) * D + d];
    fs += u;
    ss += u * img[(size_t)(b * P + t) * D + d];
  }
  __shared__ float red[4][64];
  __shared__ float sred[4];
  red[tg][l] = fs;
  const float sw = wave_sum(ss);
  if (l == 0) sred[tg] = sw;
  __syncthreads();
  if (tg == 0) {
    f_token[(size_t)b * D + d] =
        (red[0][l] + red[1][l] + red[2][l] + red[3][l]) * (1.0f / T);
    if (threadIdx.x == 0)
      atomicAdd(&s_token[b], (sred[0] + sred[1] + sred[2] + sred[3]) * (1.0f / T));
  }
}

// ---------------- text GAT via MFMA: one block (4 waves) per (b,h). N=64 ----------------
__global__ __launch_bounds__(256) void text_gat_mfma(
    const float* __restrict__ Wh, int ldw, const int* __restrict__ adj,
    const float* __restrict__ at, float* __restrict__ tgf) {
  const int h = blockIdx.x, b = blockIdx.y;
  const int tid = threadIdx.x, lane = tid & 63, w = tid >> 6;
  const int quad = lane >> 4, l15 = lane & 15;

  __shared__ unsigned short VT[64][72];    // Wh^T bf16: VT[f][n]
  __shared__ unsigned short Ps[4][16][72]; // per-wave normalized att rows (A-layout)
  __shared__ float srcs[64], dsts[64];
  __shared__ float redc[4][64];
  __shared__ float asv[64], adv[64];

  if (tid < 64) { asv[tid] = at[tid]; adv[tid] = at[64 + tid]; }
  for (int i = tid; i < 64 * 64; i += 256) {
    const int n = i >> 6, f = i & 63;
    VT[f][n] = f2bf(Wh[(size_t)(b * T + n) * ldw + h * 64 + f]);
  }
  __syncthreads();

  if (tid < 64) {
    float s = 0.f, dd = 0.f;
#pragma unroll 8
    for (int f = 0; f < 64; ++f) {
      const float wv = __uint_as_float((unsigned)VT[f][tid] << 16);
      s += wv * asv[f];
      dd += wv * adv[f];
    }
    srcs[tid] = s;
    dsts[tid] = dd;
  }
  __syncthreads();

  const int i = 16 * w + l15;
  const float si = srcs[i];
  const int* ar = adj + (size_t)b * T * T + i * 64;
  float sm = 0.f;
#pragma unroll 8
  for (int jj = 0; jj < 16; ++jj) {
    const int j = 4 * jj + quad;
    float e = si + dsts[j];
    e = (e >= 0.f) ? e : 0.2f * e;
    const float p = (ar[j] != 0) ? expf(e) : 0.f;
    sm += p;
    Ps[w][l15][j] = f2bf(p);
  }
  sm += __shfl_xor(sm, 16);
  sm += __shfl_xor(sm, 32);
  const float inv = 1.0f / sm;
#pragma unroll 8
  for (int jj = 0; jj < 16; ++jj) {
    const int j = 4 * jj + quad;
    Ps[w][l15][j] = f2bf(__uint_as_float((unsigned)Ps[w][l15][j] << 16) * inv);
  }

  floatx4 oc[4] = {};
#pragma unroll
  for (int ks = 0; ks < 2; ++ks) {
    const short8 pa = *(const short8*)&Ps[w][l15][ks * 32 + quad * 8];
#pragma unroll
    for (int nt = 0; nt < 4; ++nt) {
      const short8 bv = *(const short8*)&VT[nt * 16 + l15][ks * 32 + quad * 8];
      oc[nt] = __builtin_amdgcn_mfma_f32_16x16x32_bf16(pa, bv, oc[nt], 0, 0, 0);
    }
  }

  float accd[4] = {};
#pragma unroll
  for (int r = 0; r < 4; ++r)
#pragma unroll
    for (int nt = 0; nt < 4; ++nt) {
      const float hp = oc[nt][r];
      accd[nt] += (hp > 0.f) ? hp : (expf(hp) - 1.0f);
    }
#pragma unroll
  for (int nt = 0; nt < 4; ++nt) {
    accd[nt] += __shfl_xor(accd[nt], 16);
    accd[nt] += __shfl_xor(accd[nt], 32);
  }
  if (quad == 0) {
#pragma unroll
    for (int nt = 0; nt < 4; ++nt) redc[w][nt * 16 + l15] = accd[nt];
  }
  __syncthreads();
  if (w == 0) {
    const float tot = redc[0][lane] + redc[1][lane] + redc[2][lane] + redc[3][lane];
    tgf[b * D + h * 64 + lane] = tot * (1.0f / T);
  }
}

// ---------------- image GAT stage 1: src/dst per (node, head) ----------------
__global__ __launch_bounds__(256) void sd_kernel(
    const float* __restrict__ Wh, int ldw, const float* __restrict__ ai,
    float* __restrict__ sd) {
  const int task = blockIdx.x * 4 + (threadIdx.x >> 6);  // 0 .. 75263
  const int lane = threadIdx.x & 63;
  const int n = task / 12, h = task - n * 12;            // n in [0, 6272)
  const float v = Wh[(size_t)n * ldw + h * 64 + lane];
  float s = v * ai[lane];
  float dd = v * ai[64 + lane];
#pragma unroll
  for (int o = 32; o > 0; o >>= 1) {
    s += __shfl_xor(s, o);
    dd += __shfl_xor(dd, o);
  }
  if (lane == 0) {
    const int b = n / P, nn = n - b * P;
    float* base = sd + (size_t)(b * 12 + h) * 392 + nn;
    base[0] = s;
    base[196] = dd;
  }
}

// ---------------- image GAT stage 2: normalized exp-scores -> S (A-layout) ----------------
__global__ __launch_bounds__(256) void score_kernel(
    const float* __restrict__ sd, const int* __restrict__ adj,
    unsigned short* __restrict__ S) {
  const int w = threadIdx.x >> 6, lane = threadIdx.x & 63;
  const int i = blockIdx.x * 4 + w;            // 0..195
  const int h = blockIdx.y, b = blockIdx.z;
  const float* sdp = sd + (size_t)(b * 12 + h) * 392;
  const float si = sdp[i];
  const int* ar = adj + i * P;

  float p0 = 0.f, p1 = 0.f, p2 = 0.f, p3 = 0.f;
  {
    float e;
    e = si + sdp[196 + lane];        e = (e >= 0.f) ? e : 0.2f * e;
    if (ar[lane] != 0) p0 = expf(e);
    e = si + sdp[196 + lane + 64];   e = (e >= 0.f) ? e : 0.2f * e;
    if (ar[lane + 64] != 0) p1 = expf(e);
    e = si + sdp[196 + lane + 128];  e = (e >= 0.f) ? e : 0.2f * e;
    if (ar[lane + 128] != 0) p2 = expf(e);
    if (lane < 4) {
      e = si + sdp[196 + lane + 192]; e = (e >= 0.f) ? e : 0.2f * e;
      if (ar[lane + 192] != 0) p3 = expf(e);
    }
  }
  const float inv = 1.0f / wave_sum(p0 + p1 + p2 + p3);

  unsigned short* row = S + ((size_t)(b * 12 + h) * 196 + i) * 224;
  row[lane] = f2bf(p0 * inv);
  row[lane + 64] = f2bf(p1 * inv);
  row[lane + 128] = f2bf(p2 * inv);
  if (lane < 4) row[lane + 192] = f2bf(p3 * inv);
  else if (lane < 32) row[lane + 192] = 0;
}

// ---------------- image GAT stage 3: hp = S @ Wh via MFMA, elu, mean ----------------
__global__ __launch_bounds__(256) void image_gat_mfma(
    const float* __restrict__ Wh, int ldw, const unsigned short* __restrict__ S,
    float* __restrict__ igf) {
  const int h = blockIdx.x, b = blockIdx.y;
  const int tid = threadIdx.x, lane = tid & 63, w = tid >> 6;
  const int quad = lane >> 4, l15 = lane & 15;

  __shared__ unsigned short VT[64][232];   // Wh^T bf16: VT[f][n]
  __shared__ float redc[4][64];

  for (int i = tid; i < P * 64; i += 256) {
    const int n = i >> 6, f = i & 63;
    VT[f][n] = f2bf(Wh[(size_t)(b * P + n) * ldw + h * 64 + f]);
  }
  if (tid < 64)
    for (int c = 196; c < 224; ++c) VT[tid][c] = 0;
  __syncthreads();

  const unsigned short* Sbh = S + (size_t)(b * 12 + h) * 196 * 224;
  float accd[4] = {};

  for (int tile = w; tile < 13; tile += 4) {
    const unsigned short* Srow = Sbh + (size_t)(tile * 16 + l15) * 224;
    floatx4 oc[4] = {};
#pragma unroll
    for (int ks = 0; ks < 7; ++ks) {
      const short8 pa = *(const short8*)(Srow + ks * 32 + quad * 8);
#pragma unroll
      for (int nt = 0; nt < 4; ++nt) {
        const short8 bv = *(const short8*)&VT[nt * 16 + l15][ks * 32 + quad * 8];
        oc[nt] = __builtin_amdgcn_mfma_f32_16x16x32_bf16(pa, bv, oc[nt], 0, 0, 0);
      }
    }
#pragma unroll
    for (int r = 0; r < 4; ++r) {
      const int io = tile * 16 + quad * 4 + r;
      if (io < P) {
#pragma unroll
        for (int nt = 0; nt < 4; ++nt) {
          const float hp = oc[nt][r];
          accd[nt] += (hp > 0.f) ? hp : (expf(hp) - 1.0f);
        }
      }
    }
  }

#pragma unroll
  for (int nt = 0; nt < 4; ++nt) {
    accd[nt] += __shfl_xor(accd[nt], 16);
    accd[nt] += __shfl_xor(accd[nt], 32);
  }
  if (quad == 0) {
#pragma unroll
    for (int nt = 0; nt < 4; ++nt) redc[w][nt * 16 + l15] = accd[nt];
  }
  __syncthreads();
  if (w == 0) {
    const float tot = redc[0][lane] + redc[1][lane] + redc[2][lane] + redc[3][lane];
    igf[b * D + h * 64 + lane] = tot * (1.0f / P);
  }
}

// ---------------- f_global = clip_t @ Wp + bp : grid (12, B) ----------------
__global__ __launch_bounds__(256) void fglob_kernel(
    const float* __restrict__ clip_t, const float* __restrict__ Wp,
    const float* __restrict__ bp, float* __restrict__ fglob) {
  const int jt = blockIdx.x, b = blockIdx.y;
  const int j = threadIdx.x & 63, kc = threadIdx.x >> 6;
  float s = 0.f;
  const float* ct = clip_t + b * 512;
#pragma unroll 4
  for (int k = kc * 128; k < kc * 128 + 128; ++k)
    s += ct[k] * Wp[(size_t)k * D + jt * 64 + j];
  __shared__ float red[4][64];
  red[kc][j] = s;
  __syncthreads();
  if (kc == 0)
    fglob[b * D + jt * 64 + j] = red[0][j] + red[1][j] + red[2][j] + red[3][j] + bp[jt * 64 + j];
}

// ---------------- Xc = [f_token; tgf; fglob] @ c1w : grid (6, 96) ----------------
__global__ __launch_bounds__(256) void xc1_kernel(
    const float* __restrict__ ftok, const float* __restrict__ tgf,
    const float* __restrict__ fglob, const float* __restrict__ c1w,
    float* __restrict__ Xc) {
  const int jt = blockIdx.x;
  const int r = blockIdx.y;
  const int b = r & 31, which = r >> 5;
  const float* src = (which == 0 ? ftok : which == 1 ? tgf : fglob) + (size_t)b * D;
  const int j = threadIdx.x & 63, kc = threadIdx.x >> 6;
  const int col = jt * 64 + j;
  float s = 0.f;
#pragma unroll 4
  for (int k = kc * 192; k < kc * 192 + 192; ++k)
    s += src[k] * c1w[(size_t)k * 384 + col];
  __shared__ float red[4][64];
  red[kc][j] = s;
  __syncthreads();
  if (kc == 0)
    Xc[(size_t)r * 384 + col] = red[0][j] + red[1][j] + red[2][j] + red[3][j];
}

// ---------------- final fusion kernel: one block per b ----------------
__device__ __forceinline__ float block_sum(float v, float* red4) {
  v = wave_sum(v);
  __syncthreads();
  if ((threadIdx.x & 63) == 0) red4[threadIdx.x >> 6] = v;
  __syncthreads();
  return red4[0] + red4[1] + red4[2] + red4[3];
}

__global__ __launch_bounds__(256) void final_kernel(
    const float* __restrict__ tgf, const float* __restrict__ igf,
    const float* __restrict__ clip_t, const float* __restrict__ clip_i,
    const float* __restrict__ logit_scale, const float* __restrict__ s_token,
    const float* __restrict__ Xc,
    const float* __restrict__ f1w, const float* __restrict__ f1b,
    const float* __restrict__ f2w, const float* __restrict__ f2b,
    const float* __restrict__ c1b,
    const float* __restrict__ c2w, const float* __restrict__ c2b,
    float* __restrict__ out) {
  const int b = blockIdx.x, tid = threadIdx.x;
  __shared__ float red[4];
  __shared__ float sres[4];
  __shared__ float hid[384];

  float d0 = 0.f, d1 = 0.f, d2 = 0.f;
  for (int i = tid; i < D; i += 256) {
    float x = tgf[b * D + i], y = igf[b * D + i];
    d0 += x * y; d1 += x * x; d2 += y * y;
  }
  float dot_ti = block_sum(d0, red);
  float n_t = sqrtf(block_sum(d1, red));
  float n_i = sqrtf(block_sum(d2, red));
  float s_phrase = dot_ti / (fmaxf(n_t, 1e-8f) * fmaxf(n_i, 1e-8f));

  float c0 = 0.f, c1 = 0.f, c2 = 0.f;
  for (int i = tid; i < 512; i += 256) {
    float x = clip_t[b * 512 + i], y = clip_i[b * 512 + i];
    c0 += x * y; c1 += x * x; c2 += y * y;
  }
  float dc = block_sum(c0, red);
  float nt2 = sqrtf(block_sum(c1, red));
  float ni2 = sqrtf(block_sum(c2, red));
  float s_global = expf(logit_scale[0]) * dc / (fmaxf(nt2, 1e-8f) * fmaxf(ni2, 1e-8f));

  if (tid == 0) {
    float s3[3] = { s_token[b], s_phrase, s_global };
    float h1[16];
    for (int j = 0; j < 16; ++j) {
      float a = f1b[j];
      for (int i2 = 0; i2 < 3; ++i2) a += s3[i2] * f1w[i2 * 16 + j];
      h1[j] = 0.5f * a * (1.0f + erff(a * 0.70710678118654752f));
    }
    for (int j = 0; j < 3; ++j) {
      float a = f2b[j];
      for (int i2 = 0; i2 < 16; ++i2) a += h1[i2] * f2w[i2 * 3 + j];
      sres[j] = 1.0f / (1.0f + expf(-a));
    }
  }
  __syncthreads();
  const float w0 = sres[0], w1 = sres[1], w2 = sres[2];

  for (int j = tid; j < 384; j += 256) {
    const float a = w0 * Xc[(size_t)b * 384 + j] +
                    w1 * Xc[(size_t)(32 + b) * 384 + j] +
                    w2 * Xc[(size_t)(64 + b) * 384 + j] + c1b[j];
    hid[j] = fmaxf(a, 0.0f);
  }
  __syncthreads();

  float p0 = 0.f, p1 = 0.f;
  for (int k2 = tid; k2 < 384; k2 += 256) {
    p0 += hid[k2] * c2w[k2 * 2 + 0];
    p1 += hid[k2] * c2w[k2 * 2 + 1];
  }
  p0 = block_sum(p0, red);
  p1 = block_sum(p1, red);
  if (tid == 0) {
    out[b * 2 + 0] = p0 + c2b[0];
    out[b * 2 + 1] = p1 + c2b[1];
  }
}

// ---------------- launch ----------------
extern "C" void kernel_launch(void* const* d_in, const int* in_sizes, int n_in,
                              void* d_out, int out_size, void* d_ws, size_t ws_size,
                              hipStream_t stream) {
  const float* text   = (const float*)d_in[0];
  const float* img    = (const float*)d_in[1];
  const float* clip_t = (const float*)d_in[2];
  const float* clip_i = (const float*)d_in[3];
  const float* lscale = (const float*)d_in[4];
  const float* wq = (const float*)d_in[5];
  const float* bq = (const float*)d_in[6];
  const float* wk = (const float*)d_in[7];
  const float* bk = (const float*)d_in[8];
  const float* wv = (const float*)d_in[9];
  const float* bv = (const float*)d_in[10];
  const float* wo = (const float*)d_in[11];
  const float* bo = (const float*)d_in[12];
  const float* Wt = (const float*)d_in[13];
  const float* at = (const float*)d_in[14];
  const float* Wi = (const float*)d_in[15];
  const float* ai = (const float*)d_in[16];
  const float* Wp = (const float*)d_in[17];
  const float* bp = (const float*)d_in[18];
  const float* f1w = (const float*)d_in[19];
  const float* f1b = (const float*)d_in[20];
  const float* f2w = (const float*)d_in[21];
  const float* f2b = (const float*)d_in[22];
  const float* c1w = (const float*)d_in[23];
  const float* c1b = (const float*)d_in[24];
  const float* c2w = (const float*)d_in[25];
  const float* c2b = (const float*)d_in[26];
  const int* text_adj  = (const int*)d_in[27];
  const int* image_adj = (const int*)d_in[28];
  float* out = (float*)d_out;

  const size_t nTD = (size_t)B * T * D;   // 1,572,864
  const size_t nPD = (size_t)B * P * D;   // 4,816,896
  const size_t nWW = (size_t)D * D;       // 589,824

  // ---- workspace layout (no aliasing; ~134 MB < 256 MiB ws) ----
  float* fbuf = (float*)d_ws;
  size_t o = 0;
  float* kvw_buf = fbuf + o; o += 3 * nPD;  // [B*P][2304]: k|v|Wh_i
  float* qa_buf  = fbuf + o; o += 2 * nTD;  // [B*T][1536]: q|Wh_t
  float* upd     = fbuf + o; o += nTD;
  float* ftok    = fbuf + o; o += (size_t)B * D;
  float* stok    = fbuf + o; o += 32;
  float* tgf     = fbuf + o; o += (size_t)B * D;
  float* igf     = fbuf + o; o += (size_t)B * D;
  float* fglob   = fbuf + o; o += (size_t)B * D;
  float* bcat_t  = fbuf + o; o += 1536;
  float* bcat_i3 = fbuf + o; o += 2304;
  float* sd      = fbuf + o; o += (size_t)384 * 392;
  float* Xc      = fbuf + o; o += (size_t)96 * 384;
  unsigned short* sbuf = (unsigned short*)(fbuf + o);
  size_t so = 0;
  unsigned short* text_bf   = sbuf + so; so += nTD;
  unsigned short* img_bf    = sbuf + so; so += nPD;
  unsigned short* att_bf    = sbuf + so; so += nTD;
  unsigned short* wcat_txt  = sbuf + so; so += 2 * nWW;  // wq^T | Wt^T
  unsigned short* wcat_img3 = sbuf + so; so += 3 * nWW;  // wk^T | wv^T | Wi^T
  unsigned short* wo_t      = sbuf + so; so += nWW;
  unsigned short* S         = sbuf + so; so += (size_t)384 * 196 * 224;

  // ---- weight casts + biases + activation casts ----
  WPack wp;
  wp.src[0] = wq; wp.dst[0] = wcat_txt;
  wp.src[1] = Wt; wp.dst[1] = wcat_txt + nWW;
  wp.src[2] = wk; wp.dst[2] = wcat_img3;
  wp.src[3] = wv; wp.dst[3] = wcat_img3 + nWW;
  wp.src[4] = Wi; wp.dst[4] = wcat_img3 + 2 * nWW;
  wp.src[5] = wo; wp.dst[5] = wo_t;
  cast_transpose6<<<dim3(D / 32, D / 32, 6), 256, 0, stream>>>(wp, D, D);
  build_bias<<<12, 256, 0, stream>>>(bq, bk, bv, bcat_t, bcat_i3, stok);
  {
    const int n40 = (int)(nTD / 4), n41 = (int)(nPD / 4);
    cast_rows2<<<(n40 + n41 + 255) / 256, 256, 0, stream>>>(text, text_bf, n40, img, img_bf, n41);
  }

  const int MT = B * T;   // 2048
  const int MP = B * P;   // 6272

  // ---- fused projections: one dual launch (img3: 882 blocks, text: 192 blocks) ----
  GemmJob jimg;  // kvw = img @ [wk|wv|Wi] + [bk,bv,0]
  jimg.A = img_bf; jimg.Bt = wcat_img3; jimg.bias = bcat_i3; jimg.C = kvw_buf;
  jimg.N = 2304; jimg.K = D; jimg.colTiles = 2304 / 128;            // 18 x 49
  GemmJob jtxt;  // qa = text @ [wq|Wt] + [bq,0]
  jtxt.A = text_bf; jtxt.Bt = wcat_txt; jtxt.bias = bcat_t; jtxt.C = qa_buf;
  jtxt.N = 1536; jtxt.K = D; jtxt.colTiles = 1536 / 128;            // 12 x 16
  const int splitBlocks = (2304 / 128) * (MP / 128);                // 882
  const int totalBlocks = splitBlocks + (1536 / 128) * (MT / 128);  // 882 + 192
  gemm_mfma_dual<<<totalBlocks, 256, 0, stream>>>(jimg, jtxt, splitBlocks);

  fglob_kernel<<<dim3(12, B), 256, 0, stream>>>(clip_t, Wp, bp, fglob);

  attn_mfma<<<dim3(H, B), 256, 0, stream>>>(qa_buf, kvw_buf, att_bf);

  GemmJob jwo;   // upd = att @ wo + bo
  jwo.A = att_bf; jwo.Bt = wo_t; jwo.bias = bo; jwo.C = upd;
  jwo.N = D; jwo.K = D; jwo.colTiles = D / 128;
  gemm_mfma<<<dim3(D / 128, MT / 128), 256, 0, stream>>>(jwo);

  token_kernel<<<dim3(12, B), 256, 0, stream>>>(upd, img, ftok, stok);
  text_gat_mfma<<<dim3(H, B), 256, 0, stream>>>(qa_buf + 768, 1536, text_adj, at, tgf);

  // ---- image GAT: 3-stage pipeline on whi = kvw cols 1536.. (stride 2304) ----
  const float* whi = kvw_buf + 1536;
  sd_kernel<<<MP * 12 / 4, 256, 0, stream>>>(whi, 2304, ai, sd);
  score_kernel<<<dim3(49, H, B), 256, 0, stream>>>(sd, image_adj, S);
  image_gat_mfma<<<dim3(H, B), 256, 0, stream>>>(whi, 2304, S, igf);

  xc1_kernel<<<dim3(6, 96), 256, 0, stream>>>(ftok, tgf, fglob, c1w, Xc);
  final_kernel<<<B, 256, 0, stream>>>(tgf, igf, clip_t, clip_i, lscale, stok, Xc,
                                      f1w, f1b, f2w, f2b, c1b, c2w, c2b, out);
}

// Round 14
// 340.056 us; speedup vs baseline: 1.0367x; 1.0345x over previous
//
#include <hip/hip_runtime.h>
#include <hip/hip_bf16.h>
#include <math.h>

// Problem constants
#define B 32
#define T 64
#define P 196
#define D 768
#define H 12

typedef __attribute__((ext_vector_type(8))) short short8;
typedef __attribute__((ext_vector_type(4))) float floatx4;

// ---------------- helpers ----------------
__device__ __forceinline__ float wave_sum(float v) {
#pragma unroll
  for (int o = 32; o > 0; o >>= 1) v += __shfl_xor(v, o);
  return v;
}
__device__ __forceinline__ unsigned short f2bf(float x) {
  unsigned u = __float_as_uint(x);
  u += 0x7FFFu + ((u >> 16) & 1u);   // round-to-nearest-even
  return (unsigned short)(u >> 16);
}
__device__ __forceinline__ float bf2f(unsigned short x) {
  return __uint_as_float((unsigned)x << 16);
}
// async global->LDS, 16B per lane; LDS dest = wave-uniform base + lane*16
__device__ __forceinline__ void async_cp16(const unsigned short* g, unsigned short* l) {
  __builtin_amdgcn_global_load_lds(
      (const __attribute__((address_space(1))) unsigned int*)g,
      (__attribute__((address_space(3))) unsigned int*)l, 16, 0, 0);
}

// ---------------- cast kernels ----------------
__global__ __launch_bounds__(256) void cast_rows2(
    const float* __restrict__ X0, unsigned short* __restrict__ Y0, int n40,
    const float* __restrict__ X1, unsigned short* __restrict__ Y1, int n41) {
  int i = blockIdx.x * 256 + threadIdx.x;
  const float* X;
  unsigned short* Y;
  int idx;
  if (i < n40) { X = X0; Y = Y0; idx = i; }
  else if (i < n40 + n41) { X = X1; Y = Y1; idx = i - n40; }
  else return;
  float4 vv = ((const float4*)X)[idx];
  ushort4 o;
  o.x = f2bf(vv.x); o.y = f2bf(vv.y); o.z = f2bf(vv.z); o.w = f2bf(vv.w);
  ((ushort4*)Y)[idx] = o;
}

// 6 weights fp32 [K][N] -> bf16 [N][K], one fused launch (grid.z = weight idx)
struct WPack {
  const float* src[6];
  unsigned short* dst[6];
};
__global__ __launch_bounds__(256) void cast_transpose6(WPack p, int K, int N) {
  __shared__ float tile[32][33];
  const float* W = p.src[blockIdx.z];
  unsigned short* Wt = p.dst[blockIdx.z];
  const int tx = threadIdx.x & 31, ty = threadIdx.x >> 5;  // ty 0..7
  const int n0 = blockIdx.x * 32, k0 = blockIdx.y * 32;
#pragma unroll
  for (int r = 0; r < 4; ++r)
    tile[ty + 8 * r][tx] = W[(size_t)(k0 + ty + 8 * r) * N + n0 + tx];
  __syncthreads();
#pragma unroll
  for (int r = 0; r < 4; ++r)
    Wt[(size_t)(n0 + ty + 8 * r) * K + k0 + tx] = f2bf(tile[tx][ty + 8 * r]);
}

// biases: bt = [bq, 0] (1536), bi = [bk, bv, 0] (2304); also zero s_token
__global__ __launch_bounds__(256) void build_bias(const float* __restrict__ bq,
                                                  const float* __restrict__ bk,
                                                  const float* __restrict__ bv,
                                                  float* __restrict__ bt,
                                                  float* __restrict__ bi,
                                                  float* __restrict__ stok) {
  int i = blockIdx.x * 256 + threadIdx.x;
  if (i < 32) stok[i] = 0.f;
  if (i < 768) { bt[i] = bq[i]; bi[i] = bk[i]; }
  else if (i < 1536) { bt[i] = 0.f; bi[i] = bv[i - 768]; }
  else if (i < 2304) { bi[i] = 0.f; }
}

// ---------------- bf16 MFMA GEMM body (templated output dtype) ----------------
struct GemmJob {
  const unsigned short* A;   // [M][K] bf16
  const unsigned short* Bt;  // [N][K] bf16
  const float* bias;
  void* C;                   // fp32 or bf16 per template
  int N, K, colTiles;
};

template <bool BF16OUT>
__device__ __forceinline__ void gemm_body(const GemmJob& j, int bx, int by, int tid) {
  __shared__ unsigned short As[128][32];  // unpadded (global_load_lds dest)
  __shared__ unsigned short Bs[128][32];
  const int lane = tid & 63;
  const int w = tid >> 6;
  const int quad = lane >> 4;
  const int l15 = lane & 15;
  const int row0 = by * 128;
  const int col0 = bx * 128;
  const int m_off = (w & 1) * 64;
  const int n_off = (w >> 1) * 64;
  const int N = j.N, K = j.K;

  const int srow = 16 * w + (lane >> 2);
  const int scol = (lane & 3) * 8;
  const unsigned short* gA0 = j.A + (size_t)(row0 + srow) * K + scol;
  const unsigned short* gA1 = j.A + (size_t)(row0 + srow + 64) * K + scol;
  const unsigned short* gB0 = j.Bt + (size_t)(col0 + srow) * K + scol;
  const unsigned short* gB1 = j.Bt + (size_t)(col0 + srow + 64) * K + scol;
  unsigned short* lA0 = &As[16 * w][0];
  unsigned short* lA1 = &As[64 + 16 * w][0];
  unsigned short* lB0 = &Bs[16 * w][0];
  unsigned short* lB1 = &Bs[64 + 16 * w][0];

  floatx4 acc[4][4] = {};

  for (int k0 = 0; k0 < K; k0 += 32) {
    __syncthreads();
    async_cp16(gA0 + k0, lA0);
    async_cp16(gA1 + k0, lA1);
    async_cp16(gB0 + k0, lB0);
    async_cp16(gB1 + k0, lB1);
    __syncthreads();

    short8 af[4], bfr[4];
#pragma unroll
    for (int i = 0; i < 4; ++i)
      af[i] = *(const short8*)&As[m_off + 16 * i + l15][quad * 8];
#pragma unroll
    for (int jj = 0; jj < 4; ++jj)
      bfr[jj] = *(const short8*)&Bs[n_off + 16 * jj + l15][quad * 8];
#pragma unroll
    for (int i = 0; i < 4; ++i)
#pragma unroll
      for (int jj = 0; jj < 4; ++jj)
        acc[i][jj] = __builtin_amdgcn_mfma_f32_16x16x32_bf16(af[i], bfr[jj], acc[i][jj], 0, 0, 0);
  }

#pragma unroll
  for (int jj = 0; jj < 4; ++jj) {
    const int cg = col0 + n_off + 16 * jj + l15;
    const float bv = j.bias ? j.bias[cg] : 0.0f;
#pragma unroll
    for (int i = 0; i < 4; ++i) {
      const int rbase = row0 + m_off + 16 * i + quad * 4;
#pragma unroll
      for (int r = 0; r < 4; ++r) {
        const float val = acc[i][jj][r] + bv;
        const size_t idx = (size_t)(rbase + r) * N + cg;
        if (BF16OUT) ((unsigned short*)j.C)[idx] = f2bf(val);
        else ((float*)j.C)[idx] = val;
      }
    }
  }
}

__global__ __launch_bounds__(256) void gemm_mfma_f32(GemmJob j) {
  gemm_body<false>(j, blockIdx.x, blockIdx.y, threadIdx.x);
}

// two independent GEMMs (bf16 out) in one launch; blockIdx.x < split -> job0 else job1
__global__ __launch_bounds__(256) void gemm_mfma_dual_bf16(GemmJob j0, GemmJob j1, int split) {
  const bool first = ((int)blockIdx.x < split);
  const GemmJob& j = first ? j0 : j1;
  const int bid = first ? blockIdx.x : (blockIdx.x - split);
  const int bx = bid % j.colTiles;
  const int by = bid / j.colTiles;
  gemm_body<true>(j, bx, by, threadIdx.x);
}

// ---------------- MFMA cross attention: one block per (b,h), 4 waves ----------------
// qa: [B*T][1536] bf16 (q cols 0..767). kvw: [B*P][2304] bf16 (k 0..767, v 768..1535).
__global__ __launch_bounds__(256) void attn_mfma(
    const unsigned short* __restrict__ qa, const unsigned short* __restrict__ kvw,
    unsigned short* __restrict__ attout) {
  const int h = blockIdx.x, b = blockIdx.y;
  const int tid = threadIdx.x, lane = tid & 63, w = tid >> 6;
  const int quad = lane >> 4, l15 = lane & 15;

  __shared__ unsigned short Ks[196][72];     // K[p][d] bf16
  __shared__ unsigned short VT[64][232];     // V^T: VT[d][p]
  __shared__ unsigned short Ps[4][16][232];  // per-wave P (A-layout rows t_local)

  for (int i = tid; i < P * 64; i += 256) {
    const int p = i >> 6, d = i & 63;
    const unsigned short* row = kvw + (size_t)(b * P + p) * 2304 + h * 64 + d;
    Ks[p][d] = row[0];
    VT[d][p] = row[768];
  }
  if (tid < 64) {
    for (int c = 196; c < 224; ++c) VT[tid][c] = 0;
  }
  __syncthreads();

  short8 aq[2];
#pragma unroll
  for (int ks = 0; ks < 2; ++ks)
    aq[ks] = *(const short8*)(qa + (size_t)(b * T + 16 * w + l15) * 1536 + h * 64 +
                              32 * ks + quad * 8);

  floatx4 sc[13];
#pragma unroll
  for (int tile = 0; tile < 13; ++tile) {
    int p = tile * 16 + l15;
    if (p > 195) p = 195;
    short8 bk0 = *(const short8*)&Ks[p][quad * 8];
    short8 bk1 = *(const short8*)&Ks[p][32 + quad * 8];
    floatx4 c = {};
    c = __builtin_amdgcn_mfma_f32_16x16x32_bf16(aq[0], bk0, c, 0, 0, 0);
    c = __builtin_amdgcn_mfma_f32_16x16x32_bf16(aq[1], bk1, c, 0, 0, 0);
    sc[tile] = c;
  }

  float mx[4] = {-3.4e38f, -3.4e38f, -3.4e38f, -3.4e38f};
#pragma unroll
  for (int tile = 0; tile < 13; ++tile)
#pragma unroll
    for (int r = 0; r < 4; ++r) {
      float s = sc[tile][r] * 0.125f;
      if (tile == 12 && l15 >= 4) s = -3.0e38f;
      sc[tile][r] = s;
      mx[r] = fmaxf(mx[r], s);
    }
#pragma unroll
  for (int off = 1; off < 16; off <<= 1)
#pragma unroll
    for (int r = 0; r < 4; ++r) mx[r] = fmaxf(mx[r], __shfl_xor(mx[r], off));

  float sm[4] = {};
#pragma unroll
  for (int tile = 0; tile < 13; ++tile)
#pragma unroll
    for (int r = 0; r < 4; ++r) {
      float e = expf(sc[tile][r] - mx[r]);
      sc[tile][r] = e;
      sm[r] += e;
    }
#pragma unroll
  for (int off = 1; off < 16; off <<= 1)
#pragma unroll
    for (int r = 0; r < 4; ++r) sm[r] += __shfl_xor(sm[r], off);
  float inv[4];
#pragma unroll
  for (int r = 0; r < 4; ++r) inv[r] = 1.0f / sm[r];

#pragma unroll
  for (int tile = 0; tile < 13; ++tile)
#pragma unroll
    for (int r = 0; r < 4; ++r)
      Ps[w][quad * 4 + r][tile * 16 + l15] = f2bf(sc[tile][r] * inv[r]);
#pragma unroll
  for (int r = 0; r < 4; ++r)
    Ps[w][quad * 4 + r][208 + l15] = 0;

  __syncthreads();

  floatx4 oc[4] = {};
#pragma unroll
  for (int ks = 0; ks < 7; ++ks) {
    short8 pa = *(const short8*)&Ps[w][l15][ks * 32 + quad * 8];
#pragma unroll
    for (int nt = 0; nt < 4; ++nt) {
      short8 bv = *(const short8*)&VT[nt * 16 + l15][ks * 32 + quad * 8];
      oc[nt] = __builtin_amdgcn_mfma_f32_16x16x32_bf16(pa, bv, oc[nt], 0, 0, 0);
    }
  }

#pragma unroll
  for (int nt = 0; nt < 4; ++nt)
#pragma unroll
    for (int r = 0; r < 4; ++r)
      attout[(size_t)(b * T + 16 * w + quad * 4 + r) * 768 + h * 64 + nt * 16 + l15] =
          f2bf(oc[nt][r]);
}

// ---------------- token: grid (12, B). f_token slice + s_token partial ----------------
__global__ __launch_bounds__(256) void token_kernel(
    const float* __restrict__ upd, const float* __restrict__ img,
    float* __restrict__ f_token, float* __restrict__ s_token) {
  const int jt = blockIdx.x, b = blockIdx.y;
  const int l = threadIdx.x & 63, tg = threadIdx.x >> 6;
  const int d = jt * 64 + l;
  float fs = 0.f, ss = 0.f;
#pragma unroll 4
  for (int tt = 0; tt < 16; ++tt) {
    const int t = tg * 16 + tt;
    const float u = upd[(size_t)(b * T + t) * D + d];
    fs += u;
    ss += u * img[(size_t)(b * P + t) * D + d];
  }
  __shared__ float red[4][64];
  __shared__ float sred[4];
  red[tg][l] = fs;
  const float sw = wave_sum(ss);
  if (l == 0) sred[tg] = sw;
  __syncthreads();
  if (tg == 0) {
    f_token[(size_t)b * D + d] =
        (red[0][l] + red[1][l] + red[2][l] + red[3][l]) * (1.0f / T);
    if (threadIdx.x == 0)
      atomicAdd(&s_token[b], (sred[0] + sred[1] + sred[2] + sred[3]) * (1.0f / T));
  }
}

// ---------------- text GAT via MFMA: one block (4 waves) per (b,h). N=64 ----------------
// Wh is bf16 with row stride ldw (shorts).
__global__ __launch_bounds__(256) void text_gat_mfma(
    const unsigned short* __restrict__ Wh, int ldw, const int* __restrict__ adj,
    const float* __restrict__ at, float* __restrict__ tgf) {
  const int h = blockIdx.x, b = blockIdx.y;
  const int tid = threadIdx.x, lane = tid & 63, w = tid >> 6;
  const int quad = lane >> 4, l15 = lane & 15;

  __shared__ unsigned short VT[64][72];    // Wh^T bf16: VT[f][n]
  __shared__ unsigned short Ps[4][16][72]; // per-wave normalized att rows (A-layout)
  __shared__ float srcs[64], dsts[64];
  __shared__ float redc[4][64];
  __shared__ float asv[64], adv[64];

  if (tid < 64) { asv[tid] = at[tid]; adv[tid] = at[64 + tid]; }
  for (int i = tid; i < 64 * 64; i += 256) {
    const int n = i >> 6, f = i & 63;
    VT[f][n] = Wh[(size_t)(b * T + n) * ldw + h * 64 + f];
  }
  __syncthreads();

  if (tid < 64) {
    float s = 0.f, dd = 0.f;
#pragma unroll 8
    for (int f = 0; f < 64; ++f) {
      const float wv = bf2f(VT[f][tid]);
      s += wv * asv[f];
      dd += wv * adv[f];
    }
    srcs[tid] = s;
    dsts[tid] = dd;
  }
  __syncthreads();

  const int i = 16 * w + l15;
  const float si = srcs[i];
  const int* ar = adj + (size_t)b * T * T + i * 64;
  float sm = 0.f;
#pragma unroll 8
  for (int jj = 0; jj < 16; ++jj) {
    const int j = 4 * jj + quad;
    float e = si + dsts[j];
    e = (e >= 0.f) ? e : 0.2f * e;
    const float p = (ar[j] != 0) ? expf(e) : 0.f;
    sm += p;
    Ps[w][l15][j] = f2bf(p);
  }
  sm += __shfl_xor(sm, 16);
  sm += __shfl_xor(sm, 32);
  const float inv = 1.0f / sm;
#pragma unroll 8
  for (int jj = 0; jj < 16; ++jj) {
    const int j = 4 * jj + quad;
    Ps[w][l15][j] = f2bf(bf2f(Ps[w][l15][j]) * inv);
  }

  floatx4 oc[4] = {};
#pragma unroll
  for (int ks = 0; ks < 2; ++ks) {
    const short8 pa = *(const short8*)&Ps[w][l15][ks * 32 + quad * 8];
#pragma unroll
    for (int nt = 0; nt < 4; ++nt) {
      const short8 bv = *(const short8*)&VT[nt * 16 + l15][ks * 32 + quad * 8];
      oc[nt] = __builtin_amdgcn_mfma_f32_16x16x32_bf16(pa, bv, oc[nt], 0, 0, 0);
    }
  }

  float accd[4] = {};
#pragma unroll
  for (int r = 0; r < 4; ++r)
#pragma unroll
    for (int nt = 0; nt < 4; ++nt) {
      const float hp = oc[nt][r];
      accd[nt] += (hp > 0.f) ? hp : (expf(hp) - 1.0f);
    }
#pragma unroll
  for (int nt = 0; nt < 4; ++nt) {
    accd[nt] += __shfl_xor(accd[nt], 16);
    accd[nt] += __shfl_xor(accd[nt], 32);
  }
  if (quad == 0) {
#pragma unroll
    for (int nt = 0; nt < 4; ++nt) redc[w][nt * 16 + l15] = accd[nt];
  }
  __syncthreads();
  if (w == 0) {
    const float tot = redc[0][lane] + redc[1][lane] + redc[2][lane] + redc[3][lane];
    tgf[b * D + h * 64 + lane] = tot * (1.0f / T);
  }
}

// ---------------- image GAT stage 1: src/dst per (node, head); Wh bf16 ----------------
__global__ __launch_bounds__(256) void sd_kernel(
    const unsigned short* __restrict__ Wh, int ldw, const float* __restrict__ ai,
    float* __restrict__ sd) {
  const int task = blockIdx.x * 4 + (threadIdx.x >> 6);  // 0 .. 75263
  const int lane = threadIdx.x & 63;
  const int n = task / 12, h = task - n * 12;            // n in [0, 6272)
  const float v = bf2f(Wh[(size_t)n * ldw + h * 64 + lane]);
  float s = v * ai[lane];
  float dd = v * ai[64 + lane];
#pragma unroll
  for (int o = 32; o > 0; o >>= 1) {
    s += __shfl_xor(s, o);
    dd += __shfl_xor(dd, o);
  }
  if (lane == 0) {
    const int b = n / P, nn = n - b * P;
    float* base = sd + (size_t)(b * 12 + h) * 392 + nn;
    base[0] = s;
    base[196] = dd;
  }
}

// ---------------- image GAT stage 2: normalized exp-scores -> S (A-layout) ----------------
__global__ __launch_bounds__(256) void score_kernel(
    const float* __restrict__ sd, const int* __restrict__ adj,
    unsigned short* __restrict__ S) {
  const int w = threadIdx.x >> 6, lane = threadIdx.x & 63;
  const int i = blockIdx.x * 4 + w;            // 0..195
  const int h = blockIdx.y, b = blockIdx.z;
  const float* sdp = sd + (size_t)(b * 12 + h) * 392;
  const float si = sdp[i];
  const int* ar = adj + i * P;

  float p0 = 0.f, p1 = 0.f, p2 = 0.f, p3 = 0.f;
  {
    float e;
    e = si + sdp[196 + lane];        e = (e >= 0.f) ? e : 0.2f * e;
    if (ar[lane] != 0) p0 = expf(e);
    e = si + sdp[196 + lane + 64];   e = (e >= 0.f) ? e : 0.2f * e;
    if (ar[lane + 64] != 0) p1 = expf(e);
    e = si + sdp[196 + lane + 128];  e = (e >= 0.f) ? e : 0.2f * e;
    if (ar[lane + 128] != 0) p2 = expf(e);
    if (lane < 4) {
      e = si + sdp[196 + lane + 192]; e = (e >= 0.f) ? e : 0.2f * e;
      if (ar[lane + 192] != 0) p3 = expf(e);
    }
  }
  const float inv = 1.0f / wave_sum(p0 + p1 + p2 + p3);

  unsigned short* row = S + ((size_t)(b * 12 + h) * 196 + i) * 224;
  row[lane] = f2bf(p0 * inv);
  row[lane + 64] = f2bf(p1 * inv);
  row[lane + 128] = f2bf(p2 * inv);
  if (lane < 4) row[lane + 192] = f2bf(p3 * inv);
  else if (lane < 32) row[lane + 192] = 0;
}

// ---------------- image GAT stage 3: hp = S @ Wh via MFMA, elu, mean; Wh bf16 ----------------
__global__ __launch_bounds__(256) void image_gat_mfma(
    const unsigned short* __restrict__ Wh, int ldw, const unsigned short* __restrict__ S,
    float* __restrict__ igf) {
  const int h = blockIdx.x, b = blockIdx.y;
  const int tid = threadIdx.x, lane = tid & 63, w = tid >> 6;
  const int quad = lane >> 4, l15 = lane & 15;

  __shared__ unsigned short VT[64][232];   // Wh^T bf16: VT[f][n]
  __shared__ float redc[4][64];

  for (int i = tid; i < P * 64; i += 256) {
    const int n = i >> 6, f = i & 63;
    VT[f][n] = Wh[(size_t)(b * P + n) * ldw + h * 64 + f];
  }
  if (tid < 64)
    for (int c = 196; c < 224; ++c) VT[tid][c] = 0;
  __syncthreads();

  const unsigned short* Sbh = S + (size_t)(b * 12 + h) * 196 * 224;
  float accd[4] = {};

  for (int tile = w; tile < 13; tile += 4) {
    const unsigned short* Srow = Sbh + (size_t)(tile * 16 + l15) * 224;
    floatx4 oc[4] = {};
#pragma unroll
    for (int ks = 0; ks < 7; ++ks) {
      const short8 pa = *(const short8*)(Srow + ks * 32 + quad * 8);
#pragma unroll
      for (int nt = 0; nt < 4; ++nt) {
        const short8 bv = *(const short8*)&VT[nt * 16 + l15][ks * 32 + quad * 8];
        oc[nt] = __builtin_amdgcn_mfma_f32_16x16x32_bf16(pa, bv, oc[nt], 0, 0, 0);
      }
    }
#pragma unroll
    for (int r = 0; r < 4; ++r) {
      const int io = tile * 16 + quad * 4 + r;
      if (io < P) {
#pragma unroll
        for (int nt = 0; nt < 4; ++nt) {
          const float hp = oc[nt][r];
          accd[nt] += (hp > 0.f) ? hp : (expf(hp) - 1.0f);
        }
      }
    }
  }

#pragma unroll
  for (int nt = 0; nt < 4; ++nt) {
    accd[nt] += __shfl_xor(accd[nt], 16);
    accd[nt] += __shfl_xor(accd[nt], 32);
  }
  if (quad == 0) {
#pragma unroll
    for (int nt = 0; nt < 4; ++nt) redc[w][nt * 16 + l15] = accd[nt];
  }
  __syncthreads();
  if (w == 0) {
    const float tot = redc[0][lane] + redc[1][lane] + redc[2][lane] + redc[3][lane];
    igf[b * D + h * 64 + lane] = tot * (1.0f / P);
  }
}

// ---------------- f_global = clip_t @ Wp + bp : grid (12, B) ----------------
__global__ __launch_bounds__(256) void fglob_kernel(
    const float* __restrict__ clip_t, const float* __restrict__ Wp,
    const float* __restrict__ bp, float* __restrict__ fglob) {
  const int jt = blockIdx.x, b = blockIdx.y;
  const int j = threadIdx.x & 63, kc = threadIdx.x >> 6;
  float s = 0.f;
  const float* ct = clip_t + b * 512;
#pragma unroll 4
  for (int k = kc * 128; k < kc * 128 + 128; ++k)
    s += ct[k] * Wp[(size_t)k * D + jt * 64 + j];
  __shared__ float red[4][64];
  red[kc][j] = s;
  __syncthreads();
  if (kc == 0)
    fglob[b * D + jt * 64 + j] = red[0][j] + red[1][j] + red[2][j] + red[3][j] + bp[jt * 64 + j];
}

// ---------------- Xc = [f_token; tgf; fglob] @ c1w : grid (6, 96) ----------------
__global__ __launch_bounds__(256) void xc1_kernel(
    const float* __restrict__ ftok, const float* __restrict__ tgf,
    const float* __restrict__ fglob, const float* __restrict__ c1w,
    float* __restrict__ Xc) {
  const int jt = blockIdx.x;
  const int r = blockIdx.y;
  const int b = r & 31, which = r >> 5;
  const float* src = (which == 0 ? ftok : which == 1 ? tgf : fglob) + (size_t)b * D;
  const int j = threadIdx.x & 63, kc = threadIdx.x >> 6;
  const int col = jt * 64 + j;
  float s = 0.f;
#pragma unroll 4
  for (int k = kc * 192; k < kc * 192 + 192; ++k)
    s += src[k] * c1w[(size_t)k * 384 + col];
  __shared__ float red[4][64];
  red[kc][j] = s;
  __syncthreads();
  if (kc == 0)
    Xc[(size_t)r * 384 + col] = red[0][j] + red[1][j] + red[2][j] + red[3][j];
}

// ---------------- final fusion kernel: one block per b ----------------
__device__ __forceinline__ float block_sum(float v, float* red4) {
  v = wave_sum(v);
  __syncthreads();
  if ((threadIdx.x & 63) == 0) red4[threadIdx.x >> 6] = v;
  __syncthreads();
  return red4[0] + red4[1] + red4[2] + red4[3];
}

__global__ __launch_bounds__(256) void final_kernel(
    const float* __restrict__ tgf, const float* __restrict__ igf,
    const float* __restrict__ clip_t, const float* __restrict__ clip_i,
    const float* __restrict__ logit_scale, const float* __restrict__ s_token,
    const float* __restrict__ Xc,
    const float* __restrict__ f1w, const float* __restrict__ f1b,
    const float* __restrict__ f2w, const float* __restrict__ f2b,
    const float* __restrict__ c1b,
    const float* __restrict__ c2w, const float* __restrict__ c2b,
    float* __restrict__ out) {
  const int b = blockIdx.x, tid = threadIdx.x;
  __shared__ float red[4];
  __shared__ float sres[4];
  __shared__ float hid[384];

  float d0 = 0.f, d1 = 0.f, d2 = 0.f;
  for (int i = tid; i < D; i += 256) {
    float x = tgf[b * D + i], y = igf[b * D + i];
    d0 += x * y; d1 += x * x; d2 += y * y;
  }
  float dot_ti = block_sum(d0, red);
  float n_t = sqrtf(block_sum(d1, red));
  float n_i = sqrtf(block_sum(d2, red));
  float s_phrase = dot_ti / (fmaxf(n_t, 1e-8f) * fmaxf(n_i, 1e-8f));

  float c0 = 0.f, c1 = 0.f, c2 = 0.f;
  for (int i = tid; i < 512; i += 256) {
    float x = clip_t[b * 512 + i], y = clip_i[b * 512 + i];
    c0 += x * y; c1 += x * x; c2 += y * y;
  }
  float dc = block_sum(c0, red);
  float nt2 = sqrtf(block_sum(c1, red));
  float ni2 = sqrtf(block_sum(c2, red));
  float s_global = expf(logit_scale[0]) * dc / (fmaxf(nt2, 1e-8f) * fmaxf(ni2, 1e-8f));

  if (tid == 0) {
    float s3[3] = { s_token[b], s_phrase, s_global };
    float h1[16];
    for (int j = 0; j < 16; ++j) {
      float a = f1b[j];
      for (int i2 = 0; i2 < 3; ++i2) a += s3[i2] * f1w[i2 * 16 + j];
      h1[j] = 0.5f * a * (1.0f + erff(a * 0.70710678118654752f));
    }
    for (int j = 0; j < 3; ++j) {
      float a = f2b[j];
      for (int i2 = 0; i2 < 16; ++i2) a += h1[i2] * f2w[i2 * 3 + j];
      sres[j] = 1.0f / (1.0f + expf(-a));
    }
  }
  __syncthreads();
  const float w0 = sres[0], w1 = sres[1], w2 = sres[2];

  for (int j = tid; j < 384; j += 256) {
    const float a = w0 * Xc[(size_t)b * 384 + j] +
                    w1 * Xc[(size_t)(32 + b) * 384 + j] +
                    w2 * Xc[(size_t)(64 + b) * 384 + j] + c1b[j];
    hid[j] = fmaxf(a, 0.0f);
  }
  __syncthreads();

  float p0 = 0.f, p1 = 0.f;
  for (int k2 = tid; k2 < 384; k2 += 256) {
    p0 += hid[k2] * c2w[k2 * 2 + 0];
    p1 += hid[k2] * c2w[k2 * 2 + 1];
  }
  p0 = block_sum(p0, red);
  p1 = block_sum(p1, red);
  if (tid == 0) {
    out[b * 2 + 0] = p0 + c2b[0];
    out[b * 2 + 1] = p1 + c2b[1];
  }
}

// ---------------- launch ----------------
extern "C" void kernel_launch(void* const* d_in, const int* in_sizes, int n_in,
                              void* d_out, int out_size, void* d_ws, size_t ws_size,
                              hipStream_t stream) {
  const float* text   = (const float*)d_in[0];
  const float* img    = (const float*)d_in[1];
  const float* clip_t = (const float*)d_in[2];
  const float* clip_i = (const float*)d_in[3];
  const float* lscale = (const float*)d_in[4];
  const float* wq = (const float*)d_in[5];
  const float* bq = (const float*)d_in[6];
  const float* wk = (const float*)d_in[7];
  const float* bk = (const float*)d_in[8];
  const float* wv = (const float*)d_in[9];
  const float* bv = (const float*)d_in[10];
  const float* wo = (const float*)d_in[11];
  const float* bo = (const float*)d_in[12];
  const float* Wt = (const float*)d_in[13];
  const float* at = (const float*)d_in[14];
  const float* Wi = (const float*)d_in[15];
  const float* ai = (const float*)d_in[16];
  const float* Wp = (const float*)d_in[17];
  const float* bp = (const float*)d_in[18];
  const float* f1w = (const float*)d_in[19];
  const float* f1b = (const float*)d_in[20];
  const float* f2w = (const float*)d_in[21];
  const float* f2b = (const float*)d_in[22];
  const float* c1w = (const float*)d_in[23];
  const float* c1b = (const float*)d_in[24];
  const float* c2w = (const float*)d_in[25];
  const float* c2b = (const float*)d_in[26];
  const int* text_adj  = (const int*)d_in[27];
  const int* image_adj = (const int*)d_in[28];
  float* out = (float*)d_out;

  const size_t nTD = (size_t)B * T * D;   // 1,572,864
  const size_t nPD = (size_t)B * P * D;   // 4,816,896
  const size_t nWW = (size_t)D * D;       // 589,824

  // ---- workspace layout (no aliasing) ----
  float* fbuf = (float*)d_ws;
  size_t o = 0;
  float* upd     = fbuf + o; o += nTD;
  float* ftok    = fbuf + o; o += (size_t)B * D;
  float* stok    = fbuf + o; o += 32;
  float* tgf     = fbuf + o; o += (size_t)B * D;
  float* igf     = fbuf + o; o += (size_t)B * D;
  float* fglob   = fbuf + o; o += (size_t)B * D;
  float* bcat_t  = fbuf + o; o += 1536;
  float* bcat_i3 = fbuf + o; o += 2304;
  float* sd      = fbuf + o; o += (size_t)384 * 392;
  float* Xc      = fbuf + o; o += (size_t)96 * 384;
  unsigned short* sbuf = (unsigned short*)(fbuf + o);
  size_t so = 0;
  unsigned short* kvw_bf    = sbuf + so; so += 3 * nPD;  // [B*P][2304] bf16: k|v|Wh_i
  unsigned short* qa_bf     = sbuf + so; so += 2 * nTD;  // [B*T][1536] bf16: q|Wh_t
  unsigned short* text_bf   = sbuf + so; so += nTD;
  unsigned short* img_bf    = sbuf + so; so += nPD;
  unsigned short* att_bf    = sbuf + so; so += nTD;
  unsigned short* wcat_txt  = sbuf + so; so += 2 * nWW;  // wq^T | Wt^T
  unsigned short* wcat_img3 = sbuf + so; so += 3 * nWW;  // wk^T | wv^T | Wi^T
  unsigned short* wo_t      = sbuf + so; so += nWW;
  unsigned short* S         = sbuf + so; so += (size_t)384 * 196 * 224;

  // ---- weight casts + biases + activation casts ----
  WPack wp;
  wp.src[0] = wq; wp.dst[0] = wcat_txt;
  wp.src[1] = Wt; wp.dst[1] = wcat_txt + nWW;
  wp.src[2] = wk; wp.dst[2] = wcat_img3;
  wp.src[3] = wv; wp.dst[3] = wcat_img3 + nWW;
  wp.src[4] = Wi; wp.dst[4] = wcat_img3 + 2 * nWW;
  wp.src[5] = wo; wp.dst[5] = wo_t;
  cast_transpose6<<<dim3(D / 32, D / 32, 6), 256, 0, stream>>>(wp, D, D);
  build_bias<<<12, 256, 0, stream>>>(bq, bk, bv, bcat_t, bcat_i3, stok);
  {
    const int n40 = (int)(nTD / 4), n41 = (int)(nPD / 4);
    cast_rows2<<<(n40 + n41 + 255) / 256, 256, 0, stream>>>(text, text_bf, n40, img, img_bf, n41);
  }

  const int MT = B * T;   // 2048
  const int MP = B * P;   // 6272

  // ---- fused projections (bf16 C output): one dual launch ----
  GemmJob jimg;  // kvw_bf = img @ [wk|wv|Wi] + [bk,bv,0]
  jimg.A = img_bf; jimg.Bt = wcat_img3; jimg.bias = bcat_i3; jimg.C = kvw_bf;
  jimg.N = 2304; jimg.K = D; jimg.colTiles = 2304 / 128;            // 18 x 49
  GemmJob jtxt;  // qa_bf = text @ [wq|Wt] + [bq,0]
  jtxt.A = text_bf; jtxt.Bt = wcat_txt; jtxt.bias = bcat_t; jtxt.C = qa_bf;
  jtxt.N = 1536; jtxt.K = D; jtxt.colTiles = 1536 / 128;            // 12 x 16
  const int splitBlocks = (2304 / 128) * (MP / 128);                // 882
  const int totalBlocks = splitBlocks + (1536 / 128) * (MT / 128);  // 882 + 192
  gemm_mfma_dual_bf16<<<totalBlocks, 256, 0, stream>>>(jimg, jtxt, splitBlocks);

  fglob_kernel<<<dim3(12, B), 256, 0, stream>>>(clip_t, Wp, bp, fglob);

  attn_mfma<<<dim3(H, B), 256, 0, stream>>>(qa_bf, kvw_bf, att_bf);

  GemmJob jwo;   // upd = att @ wo + bo (fp32 out)
  jwo.A = att_bf; jwo.Bt = wo_t; jwo.bias = bo; jwo.C = upd;
  jwo.N = D; jwo.K = D; jwo.colTiles = D / 128;
  gemm_mfma_f32<<<dim3(D / 128, MT / 128), 256, 0, stream>>>(jwo);

  token_kernel<<<dim3(12, B), 256, 0, stream>>>(upd, img, ftok, stok);
  text_gat_mfma<<<dim3(H, B), 256, 0, stream>>>(qa_bf + 768, 1536, text_adj, at, tgf);

  // ---- image GAT: 3-stage pipeline on whi_bf = kvw_bf cols 1536.. (stride 2304) ----
  const unsigned short* whi_bf = kvw_bf + 1536;
  sd_kernel<<<MP * 12 / 4, 256, 0, stream>>>(whi_bf, 2304, ai, sd);
  score_kernel<<<dim3(49, H, B), 256, 0, stream>>>(sd, image_adj, S);
  image_gat_mfma<<<dim3(H, B), 256, 0, stream>>>(whi_bf, 2304, S, igf);

  xc1_kernel<<<dim3(6, 96), 256, 0, stream>>>(ftok, tgf, fglob, c1w, Xc);
  final_kernel<<<B, 256, 0, stream>>>(tgf, igf, clip_t, clip_i, lscale, stok, Xc,
                                      f1w, f1b, f2w, f2b, c1b, c2w, c2b, out);
}

// Round 15
// 330.424 us; speedup vs baseline: 1.0670x; 1.0292x over previous
//
#include <hip/hip_runtime.h>
#include <hip/hip_bf16.h>
#include <math.h>

// Problem constants
#define B 32
#define T 64
#define P 196
#define D 768
#define H 12

typedef __attribute__((ext_vector_type(8))) short short8;
typedef __attribute__((ext_vector_type(4))) float floatx4;

// ---------------- helpers ----------------
__device__ __forceinline__ float wave_sum(float v) {
#pragma unroll
  for (int o = 32; o > 0; o >>= 1) v += __shfl_xor(v, o);
  return v;
}
__device__ __forceinline__ unsigned short f2bf(float x) {
  unsigned u = __float_as_uint(x);
  u += 0x7FFFu + ((u >> 16) & 1u);   // round-to-nearest-even
  return (unsigned short)(u >> 16);
}
__device__ __forceinline__ float bf2f(unsigned short x) {
  return __uint_as_float((unsigned)x << 16);
}
// async global->LDS, 16B per lane; LDS dest = wave-uniform base + lane*16
__device__ __forceinline__ void async_cp16(const unsigned short* g, unsigned short* l) {
  __builtin_amdgcn_global_load_lds(
      (const __attribute__((address_space(1))) unsigned int*)g,
      (__attribute__((address_space(3))) unsigned int*)l, 16, 0, 0);
}

// ---------------- cast kernels ----------------
__global__ __launch_bounds__(256) void cast_rows2(
    const float* __restrict__ X0, unsigned short* __restrict__ Y0, int n40,
    const float* __restrict__ X1, unsigned short* __restrict__ Y1, int n41) {
  int i = blockIdx.x * 256 + threadIdx.x;
  const float* X;
  unsigned short* Y;
  int idx;
  if (i < n40) { X = X0; Y = Y0; idx = i; }
  else if (i < n40 + n41) { X = X1; Y = Y1; idx = i - n40; }
  else return;
  float4 vv = ((const float4*)X)[idx];
  ushort4 o;
  o.x = f2bf(vv.x); o.y = f2bf(vv.y); o.z = f2bf(vv.z); o.w = f2bf(vv.w);
  ((ushort4*)Y)[idx] = o;
}

// 6 weights fp32 [K][N] -> bf16 [N][K], one fused launch (grid.z = weight idx)
struct WPack {
  const float* src[6];
  unsigned short* dst[6];
};
__global__ __launch_bounds__(256) void cast_transpose6(WPack p, int K, int N) {
  __shared__ float tile[32][33];
  const float* W = p.src[blockIdx.z];
  unsigned short* Wt = p.dst[blockIdx.z];
  const int tx = threadIdx.x & 31, ty = threadIdx.x >> 5;  // ty 0..7
  const int n0 = blockIdx.x * 32, k0 = blockIdx.y * 32;
#pragma unroll
  for (int r = 0; r < 4; ++r)
    tile[ty + 8 * r][tx] = W[(size_t)(k0 + ty + 8 * r) * N + n0 + tx];
  __syncthreads();
#pragma unroll
  for (int r = 0; r < 4; ++r)
    Wt[(size_t)(n0 + ty + 8 * r) * K + k0 + tx] = f2bf(tile[tx][ty + 8 * r]);
}

// biases: bt = [bq, 0] (1536), bi = [bk, bv, 0] (2304); also zero s_token
__global__ __launch_bounds__(256) void build_bias(const float* __restrict__ bq,
                                                  const float* __restrict__ bk,
                                                  const float* __restrict__ bv,
                                                  float* __restrict__ bt,
                                                  float* __restrict__ bi,
                                                  float* __restrict__ stok) {
  int i = blockIdx.x * 256 + threadIdx.x;
  if (i < 32) stok[i] = 0.f;
  if (i < 768) { bt[i] = bq[i]; bi[i] = bk[i]; }
  else if (i < 1536) { bt[i] = 0.f; bi[i] = bv[i - 768]; }
  else if (i < 2304) { bi[i] = 0.f; }
}

// ---------------- bf16 MFMA GEMM body (templated output dtype) ----------------
struct GemmJob {
  const unsigned short* A;   // [M][*] bf16, row stride lda
  const unsigned short* Bt;  // [N][*] bf16, row stride ldb
  const float* bias;
  void* C;                   // fp32 or bf16 per template
  int N, K, lda, ldb, colTiles;
};

template <bool BF16OUT>
__device__ __forceinline__ void gemm_body(const GemmJob& j, int bx, int by, int tid) {
  __shared__ unsigned short As[128][32];  // unpadded (global_load_lds dest)
  __shared__ unsigned short Bs[128][32];
  const int lane = tid & 63;
  const int w = tid >> 6;
  const int quad = lane >> 4;
  const int l15 = lane & 15;
  const int row0 = by * 128;
  const int col0 = bx * 128;
  const int m_off = (w & 1) * 64;
  const int n_off = (w >> 1) * 64;
  const int N = j.N, K = j.K;

  const int srow = 16 * w + (lane >> 2);
  const int scol = (lane & 3) * 8;
  const unsigned short* gA0 = j.A + (size_t)(row0 + srow) * j.lda + scol;
  const unsigned short* gA1 = j.A + (size_t)(row0 + srow + 64) * j.lda + scol;
  const unsigned short* gB0 = j.Bt + (size_t)(col0 + srow) * j.ldb + scol;
  const unsigned short* gB1 = j.Bt + (size_t)(col0 + srow + 64) * j.ldb + scol;
  unsigned short* lA0 = &As[16 * w][0];
  unsigned short* lA1 = &As[64 + 16 * w][0];
  unsigned short* lB0 = &Bs[16 * w][0];
  unsigned short* lB1 = &Bs[64 + 16 * w][0];

  floatx4 acc[4][4] = {};

  for (int k0 = 0; k0 < K; k0 += 32) {
    __syncthreads();
    async_cp16(gA0 + k0, lA0);
    async_cp16(gA1 + k0, lA1);
    async_cp16(gB0 + k0, lB0);
    async_cp16(gB1 + k0, lB1);
    __syncthreads();

    short8 af[4], bfr[4];
#pragma unroll
    for (int i = 0; i < 4; ++i)
      af[i] = *(const short8*)&As[m_off + 16 * i + l15][quad * 8];
#pragma unroll
    for (int jj = 0; jj < 4; ++jj)
      bfr[jj] = *(const short8*)&Bs[n_off + 16 * jj + l15][quad * 8];
#pragma unroll
    for (int i = 0; i < 4; ++i)
#pragma unroll
      for (int jj = 0; jj < 4; ++jj)
        acc[i][jj] = __builtin_amdgcn_mfma_f32_16x16x32_bf16(af[i], bfr[jj], acc[i][jj], 0, 0, 0);
  }

#pragma unroll
  for (int jj = 0; jj < 4; ++jj) {
    const int cg = col0 + n_off + 16 * jj + l15;
    const float bv = j.bias ? j.bias[cg] : 0.0f;
#pragma unroll
    for (int i = 0; i < 4; ++i) {
      const int rbase = row0 + m_off + 16 * i + quad * 4;
#pragma unroll
      for (int r = 0; r < 4; ++r) {
        const float val = acc[i][jj][r] + bv;
        const size_t idx = (size_t)(rbase + r) * N + cg;
        if (BF16OUT) ((unsigned short*)j.C)[idx] = f2bf(val);
        else ((float*)j.C)[idx] = val;
      }
    }
  }
}

// two independent GEMMs in one launch; blockIdx.x < split -> job0 else job1
__global__ __launch_bounds__(256) void gemm_mfma_dual_bf16(GemmJob j0, GemmJob j1, int split) {
  const bool first = ((int)blockIdx.x < split);
  const GemmJob& j = first ? j0 : j1;
  const int bid = first ? blockIdx.x : (blockIdx.x - split);
  const int bx = bid % j.colTiles;
  const int by = bid / j.colTiles;
  gemm_body<true>(j, bx, by, threadIdx.x);
}

__global__ __launch_bounds__(256) void gemm_mfma_dual_f32(GemmJob j0, GemmJob j1, int split) {
  const bool first = ((int)blockIdx.x < split);
  const GemmJob& j = first ? j0 : j1;
  const int bid = first ? blockIdx.x : (blockIdx.x - split);
  const int bx = bid % j.colTiles;
  const int by = bid / j.colTiles;
  gemm_body<false>(j, bx, by, threadIdx.x);
}

// ---------------- MFMA cross attention: one block per (b,h), 4 waves ----------------
// qa: [B*T][1536] bf16 (q cols 0..767). kvw: [B*P][2304] bf16 (k 0..767, v 768..1535).
__global__ __launch_bounds__(256) void attn_mfma(
    const unsigned short* __restrict__ qa, const unsigned short* __restrict__ kvw,
    unsigned short* __restrict__ attout) {
  const int h = blockIdx.x, b = blockIdx.y;
  const int tid = threadIdx.x, lane = tid & 63, w = tid >> 6;
  const int quad = lane >> 4, l15 = lane & 15;

  __shared__ unsigned short Ks[196][72];     // K[p][d] bf16
  __shared__ unsigned short VT[64][232];     // V^T: VT[d][p]
  __shared__ unsigned short Ps[4][16][232];  // per-wave P (A-layout rows t_local)

  // vectorized staging: thread handles (p, d-group of 8). short8 loads (16B),
  // b128 LDS write for K, 8-way transpose scatter for V^T.
  for (int i = tid; i < P * 8; i += 256) {
    const int p = i >> 3, dg = i & 7;
    const unsigned short* row = kvw + (size_t)(b * P + p) * 2304 + h * 64 + dg * 8;
    const short8 k8 = *(const short8*)row;
    *(short8*)&Ks[p][dg * 8] = k8;
    const short8 v8 = *(const short8*)(row + 768);
#pragma unroll
    for (int z = 0; z < 8; ++z) VT[dg * 8 + z][p] = (unsigned short)v8[z];
  }
  if (tid < 64) {
    for (int c = 196; c < 224; ++c) VT[tid][c] = 0;
  }
  __syncthreads();

  short8 aq[2];
#pragma unroll
  for (int ks = 0; ks < 2; ++ks)
    aq[ks] = *(const short8*)(qa + (size_t)(b * T + 16 * w + l15) * 1536 + h * 64 +
                              32 * ks + quad * 8);

  floatx4 sc[13];
#pragma unroll
  for (int tile = 0; tile < 13; ++tile) {
    int p = tile * 16 + l15;
    if (p > 195) p = 195;
    short8 bk0 = *(const short8*)&Ks[p][quad * 8];
    short8 bk1 = *(const short8*)&Ks[p][32 + quad * 8];
    floatx4 c = {};
    c = __builtin_amdgcn_mfma_f32_16x16x32_bf16(aq[0], bk0, c, 0, 0, 0);
    c = __builtin_amdgcn_mfma_f32_16x16x32_bf16(aq[1], bk1, c, 0, 0, 0);
    sc[tile] = c;
  }

  float mx[4] = {-3.4e38f, -3.4e38f, -3.4e38f, -3.4e38f};
#pragma unroll
  for (int tile = 0; tile < 13; ++tile)
#pragma unroll
    for (int r = 0; r < 4; ++r) {
      float s = sc[tile][r] * 0.125f;
      if (tile == 12 && l15 >= 4) s = -3.0e38f;
      sc[tile][r] = s;
      mx[r] = fmaxf(mx[r], s);
    }
#pragma unroll
  for (int off = 1; off < 16; off <<= 1)
#pragma unroll
    for (int r = 0; r < 4; ++r) mx[r] = fmaxf(mx[r], __shfl_xor(mx[r], off));

  float sm[4] = {};
#pragma unroll
  for (int tile = 0; tile < 13; ++tile)
#pragma unroll
    for (int r = 0; r < 4; ++r) {
      float e = expf(sc[tile][r] - mx[r]);
      sc[tile][r] = e;
      sm[r] += e;
    }
#pragma unroll
  for (int off = 1; off < 16; off <<= 1)
#pragma unroll
    for (int r = 0; r < 4; ++r) sm[r] += __shfl_xor(sm[r], off);
  float inv[4];
#pragma unroll
  for (int r = 0; r < 4; ++r) inv[r] = 1.0f / sm[r];

#pragma unroll
  for (int tile = 0; tile < 13; ++tile)
#pragma unroll
    for (int r = 0; r < 4; ++r)
      Ps[w][quad * 4 + r][tile * 16 + l15] = f2bf(sc[tile][r] * inv[r]);
#pragma unroll
  for (int r = 0; r < 4; ++r)
    Ps[w][quad * 4 + r][208 + l15] = 0;

  __syncthreads();

  floatx4 oc[4] = {};
#pragma unroll
  for (int ks = 0; ks < 7; ++ks) {
    short8 pa = *(const short8*)&Ps[w][l15][ks * 32 + quad * 8];
#pragma unroll
    for (int nt = 0; nt < 4; ++nt) {
      short8 bv = *(const short8*)&VT[nt * 16 + l15][ks * 32 + quad * 8];
      oc[nt] = __builtin_amdgcn_mfma_f32_16x16x32_bf16(pa, bv, oc[nt], 0, 0, 0);
    }
  }

#pragma unroll
  for (int nt = 0; nt < 4; ++nt)
#pragma unroll
    for (int r = 0; r < 4; ++r)
      attout[(size_t)(b * T + 16 * w + quad * 4 + r) * 768 + h * 64 + nt * 16 + l15] =
          f2bf(oc[nt][r]);
}

// ---------------- token: grid (12, B). upd = upd0 + upd1 (split-K partials) ----------------
__global__ __launch_bounds__(256) void token_kernel(
    const float* __restrict__ upd0, const float* __restrict__ upd1,
    const float* __restrict__ img,
    float* __restrict__ f_token, float* __restrict__ s_token) {
  const int jt = blockIdx.x, b = blockIdx.y;
  const int l = threadIdx.x & 63, tg = threadIdx.x >> 6;
  const int d = jt * 64 + l;
  float fs = 0.f, ss = 0.f;
#pragma unroll 4
  for (int tt = 0; tt < 16; ++tt) {
    const int t = tg * 16 + tt;
    const size_t idx = (size_t)(b * T + t) * D + d;
    const float u = upd0[idx] + upd1[idx];
    fs += u;
    ss += u * img[(size_t)(b * P + t) * D + d];
  }
  __shared__ float red[4][64];
  __shared__ float sred[4];
  red[tg][l] = fs;
  const float sw = wave_sum(ss);
  if (l == 0) sred[tg] = sw;
  __syncthreads();
  if (tg == 0) {
    f_token[(size_t)b * D + d] =
        (red[0][l] + red[1][l] + red[2][l] + red[3][l]) * (1.0f / T);
    if (threadIdx.x == 0)
      atomicAdd(&s_token[b], (sred[0] + sred[1] + sred[2] + sred[3]) * (1.0f / T));
  }
}

// ---------------- text GAT via MFMA: one block (4 waves) per (b,h). N=64 ----------------
__global__ __launch_bounds__(256) void text_gat_mfma(
    const unsigned short* __restrict__ Wh, int ldw, const int* __restrict__ adj,
    const float* __restrict__ at, float* __restrict__ tgf) {
  const int h = blockIdx.x, b = blockIdx.y;
  const int tid = threadIdx.x, lane = tid & 63, w = tid >> 6;
  const int quad = lane >> 4, l15 = lane & 15;

  __shared__ unsigned short VT[64][72];    // Wh^T bf16: VT[f][n]
  __shared__ unsigned short Ps[4][16][72]; // per-wave normalized att rows (A-layout)
  __shared__ float srcs[64], dsts[64];
  __shared__ float redc[4][64];
  __shared__ float asv[64], adv[64];

  if (tid < 64) { asv[tid] = at[tid]; adv[tid] = at[64 + tid]; }
  for (int i = tid; i < 64 * 64; i += 256) {
    const int n = i >> 6, f = i & 63;
    VT[f][n] = Wh[(size_t)(b * T + n) * ldw + h * 64 + f];
  }
  __syncthreads();

  if (tid < 64) {
    float s = 0.f, dd = 0.f;
#pragma unroll 8
    for (int f = 0; f < 64; ++f) {
      const float wv = bf2f(VT[f][tid]);
      s += wv * asv[f];
      dd += wv * adv[f];
    }
    srcs[tid] = s;
    dsts[tid] = dd;
  }
  __syncthreads();

  const int i = 16 * w + l15;
  const float si = srcs[i];
  const int* ar = adj + (size_t)b * T * T + i * 64;
  float sm = 0.f;
#pragma unroll 8
  for (int jj = 0; jj < 16; ++jj) {
    const int j = 4 * jj + quad;
    float e = si + dsts[j];
    e = (e >= 0.f) ? e : 0.2f * e;
    const float p = (ar[j] != 0) ? expf(e) : 0.f;
    sm += p;
    Ps[w][l15][j] = f2bf(p);
  }
  sm += __shfl_xor(sm, 16);
  sm += __shfl_xor(sm, 32);
  const float inv = 1.0f / sm;
#pragma unroll 8
  for (int jj = 0; jj < 16; ++jj) {
    const int j = 4 * jj + quad;
    Ps[w][l15][j] = f2bf(bf2f(Ps[w][l15][j]) * inv);
  }

  floatx4 oc[4] = {};
#pragma unroll
  for (int ks = 0; ks < 2; ++ks) {
    const short8 pa = *(const short8*)&Ps[w][l15][ks * 32 + quad * 8];
#pragma unroll
    for (int nt = 0; nt < 4; ++nt) {
      const short8 bv = *(const short8*)&VT[nt * 16 + l15][ks * 32 + quad * 8];
      oc[nt] = __builtin_amdgcn_mfma_f32_16x16x32_bf16(pa, bv, oc[nt], 0, 0, 0);
    }
  }

  float accd[4] = {};
#pragma unroll
  for (int r = 0; r < 4; ++r)
#pragma unroll
    for (int nt = 0; nt < 4; ++nt) {
      const float hp = oc[nt][r];
      accd[nt] += (hp > 0.f) ? hp : (expf(hp) - 1.0f);
    }
#pragma unroll
  for (int nt = 0; nt < 4; ++nt) {
    accd[nt] += __shfl_xor(accd[nt], 16);
    accd[nt] += __shfl_xor(accd[nt], 32);
  }
  if (quad == 0) {
#pragma unroll
    for (int nt = 0; nt < 4; ++nt) redc[w][nt * 16 + l15] = accd[nt];
  }
  __syncthreads();
  if (w == 0) {
    const float tot = redc[0][lane] + redc[1][lane] + redc[2][lane] + redc[3][lane];
    tgf[b * D + h * 64 + lane] = tot * (1.0f / T);
  }
}

// ---------------- image GAT stage 1: src/dst per (node, head); Wh bf16 ----------------
__global__ __launch_bounds__(256) void sd_kernel(
    const unsigned short* __restrict__ Wh, int ldw, const float* __restrict__ ai,
    float* __restrict__ sd) {
  const int task = blockIdx.x * 4 + (threadIdx.x >> 6);  // 0 .. 75263
  const int lane = threadIdx.x & 63;
  const int n = task / 12, h = task - n * 12;            // n in [0, 6272)
  const float v = bf2f(Wh[(size_t)n * ldw + h * 64 + lane]);
  float s = v * ai[lane];
  float dd = v * ai[64 + lane];
#pragma unroll
  for (int o = 32; o > 0; o >>= 1) {
    s += __shfl_xor(s, o);
    dd += __shfl_xor(dd, o);
  }
  if (lane == 0) {
    const int b = n / P, nn = n - b * P;
    float* base = sd + (size_t)(b * 12 + h) * 392 + nn;
    base[0] = s;
    base[196] = dd;
  }
}

// ---------------- image GAT stage 2: normalized exp-scores -> S (A-layout) ----------------
__global__ __launch_bounds__(256) void score_kernel(
    const float* __restrict__ sd, const int* __restrict__ adj,
    unsigned short* __restrict__ S) {
  const int w = threadIdx.x >> 6, lane = threadIdx.x & 63;
  const int i = blockIdx.x * 4 + w;            // 0..195
  const int h = blockIdx.y, b = blockIdx.z;
  const float* sdp = sd + (size_t)(b * 12 + h) * 392;
  const float si = sdp[i];
  const int* ar = adj + i * P;

  float p0 = 0.f, p1 = 0.f, p2 = 0.f, p3 = 0.f;
  {
    float e;
    e = si + sdp[196 + lane];        e = (e >= 0.f) ? e : 0.2f * e;
    if (ar[lane] != 0) p0 = expf(e);
    e = si + sdp[196 + lane + 64];   e = (e >= 0.f) ? e : 0.2f * e;
    if (ar[lane + 64] != 0) p1 = expf(e);
    e = si + sdp[196 + lane + 128];  e = (e >= 0.f) ? e : 0.2f * e;
    if (ar[lane + 128] != 0) p2 = expf(e);
    if (lane < 4) {
      e = si + sdp[196 + lane + 192]; e = (e >= 0.f) ? e : 0.2f * e;
      if (ar[lane + 192] != 0) p3 = expf(e);
    }
  }
  const float inv = 1.0f / wave_sum(p0 + p1 + p2 + p3);

  unsigned short* row = S + ((size_t)(b * 12 + h) * 196 + i) * 224;
  row[lane] = f2bf(p0 * inv);
  row[lane + 64] = f2bf(p1 * inv);
  row[lane + 128] = f2bf(p2 * inv);
  if (lane < 4) row[lane + 192] = f2bf(p3 * inv);
  else if (lane < 32) row[lane + 192] = 0;
}

// ---------------- image GAT stage 3: hp = S @ Wh via MFMA, elu, mean; Wh bf16 ----------------
__global__ __launch_bounds__(256) void image_gat_mfma(
    const unsigned short* __restrict__ Wh, int ldw, const unsigned short* __restrict__ S,
    float* __restrict__ igf) {
  const int h = blockIdx.x, b = blockIdx.y;
  const int tid = threadIdx.x, lane = tid & 63, w = tid >> 6;
  const int quad = lane >> 4, l15 = lane & 15;

  __shared__ unsigned short VT[64][232];   // Wh^T bf16: VT[f][n]
  __shared__ float redc[4][64];

  for (int i = tid; i < P * 64; i += 256) {
    const int n = i >> 6, f = i & 63;
    VT[f][n] = Wh[(size_t)(b * P + n) * ldw + h * 64 + f];
  }
  if (tid < 64)
    for (int c = 196; c < 224; ++c) VT[tid][c] = 0;
  __syncthreads();

  const unsigned short* Sbh = S + (size_t)(b * 12 + h) * 196 * 224;
  float accd[4] = {};

  for (int tile = w; tile < 13; tile += 4) {
    const unsigned short* Srow = Sbh + (size_t)(tile * 16 + l15) * 224;
    floatx4 oc[4] = {};
#pragma unroll
    for (int ks = 0; ks < 7; ++ks) {
      const short8 pa = *(const short8*)(Srow + ks * 32 + quad * 8);
#pragma unroll
      for (int nt = 0; nt < 4; ++nt) {
        const short8 bv = *(const short8*)&VT[nt * 16 + l15][ks * 32 + quad * 8];
        oc[nt] = __builtin_amdgcn_mfma_f32_16x16x32_bf16(pa, bv, oc[nt], 0, 0, 0);
      }
    }
#pragma unroll
    for (int r = 0; r < 4; ++r) {
      const int io = tile * 16 + quad * 4 + r;
      if (io < P) {
#pragma unroll
        for (int nt = 0; nt < 4; ++nt) {
          const float hp = oc[nt][r];
          accd[nt] += (hp > 0.f) ? hp : (expf(hp) - 1.0f);
        }
      }
    }
  }

#pragma unroll
  for (int nt = 0; nt < 4; ++nt) {
    accd[nt] += __shfl_xor(accd[nt], 16);
    accd[nt] += __shfl_xor(accd[nt], 32);
  }
  if (quad == 0) {
#pragma unroll
    for (int nt = 0; nt < 4; ++nt) redc[w][nt * 16 + l15] = accd[nt];
  }
  __syncthreads();
  if (w == 0) {
    const float tot = redc[0][lane] + redc[1][lane] + redc[2][lane] + redc[3][lane];
    igf[b * D + h * 64 + lane] = tot * (1.0f / P);
  }
}

// ---------------- f_global = clip_t @ Wp + bp : grid (12, B) ----------------
__global__ __launch_bounds__(256) void fglob_kernel(
    const float* __restrict__ clip_t, const float* __restrict__ Wp,
    const float* __restrict__ bp, float* __restrict__ fglob) {
  const int jt = blockIdx.x, b = blockIdx.y;
  const int j = threadIdx.x & 63, kc = threadIdx.x >> 6;
  float s = 0.f;
  const float* ct = clip_t + b * 512;
#pragma unroll 4
  for (int k = kc * 128; k < kc * 128 + 128; ++k)
    s += ct[k] * Wp[(size_t)k * D + jt * 64 + j];
  __shared__ float red[4][64];
  red[kc][j] = s;
  __syncthreads();
  if (kc == 0)
    fglob[b * D + jt * 64 + j] = red[0][j] + red[1][j] + red[2][j] + red[3][j] + bp[jt * 64 + j];
}

// ---------------- Xc = [f_token; tgf; fglob] @ c1w : grid (6, 96) ----------------
__global__ __launch_bounds__(256) void xc1_kernel(
    const float* __restrict__ ftok, const float* __restrict__ tgf,
    const float* __restrict__ fglob, const float* __restrict__ c1w,
    float* __restrict__ Xc) {
  const int jt = blockIdx.x;
  const int r = blockIdx.y;
  const int b = r & 31, which = r >> 5;
  const float* src = (which == 0 ? ftok : which == 1 ? tgf : fglob) + (size_t)b * D;
  const int j = threadIdx.x & 63, kc = threadIdx.x >> 6;
  const int col = jt * 64 + j;
  float s = 0.f;
#pragma unroll 4
  for (int k = kc * 192; k < kc * 192 + 192; ++k)
    s += src[k] * c1w[(size_t)k * 384 + col];
  __shared__ float red[4][64];
  red[kc][j] = s;
  __syncthreads();
  if (kc == 0)
    Xc[(size_t)r * 384 + col] = red[0][j] + red[1][j] + red[2][j] + red[3][j];
}

// ---------------- final fusion kernel: one block per b ----------------
__device__ __forceinline__ float block_sum(float v, float* red4) {
  v = wave_sum(v);
  __syncthreads();
  if ((threadIdx.x & 63) == 0) red4[threadIdx.x >> 6] = v;
  __syncthreads();
  return red4[0] + red4[1] + red4[2] + red4[3];
}

__global__ __launch_bounds__(256) void final_kernel(
    const float* __restrict__ tgf, const float* __restrict__ igf,
    const float* __restrict__ clip_t, const float* __restrict__ clip_i,
    const float* __restrict__ logit_scale, const float* __restrict__ s_token,
    const float* __restrict__ Xc,
    const float* __restrict__ f1w, const float* __restrict__ f1b,
    const float* __restrict__ f2w, const float* __restrict__ f2b,
    const float* __restrict__ c1b,
    const float* __restrict__ c2w, const float* __restrict__ c2b,
    float* __restrict__ out) {
  const int b = blockIdx.x, tid = threadIdx.x;
  __shared__ float red[4];
  __shared__ float sres[4];
  __shared__ float hid[384];

  float d0 = 0.f, d1 = 0.f, d2 = 0.f;
  for (int i = tid; i < D; i += 256) {
    float x = tgf[b * D + i], y = igf[b * D + i];
    d0 += x * y; d1 += x * x; d2 += y * y;
  }
  float dot_ti = block_sum(d0, red);
  float n_t = sqrtf(block_sum(d1, red));
  float n_i = sqrtf(block_sum(d2, red));
  float s_phrase = dot_ti / (fmaxf(n_t, 1e-8f) * fmaxf(n_i, 1e-8f));

  float c0 = 0.f, c1 = 0.f, c2 = 0.f;
  for (int i = tid; i < 512; i += 256) {
    float x = clip_t[b * 512 + i], y = clip_i[b * 512 + i];
    c0 += x * y; c1 += x * x; c2 += y * y;
  }
  float dc = block_sum(c0, red);
  float nt2 = sqrtf(block_sum(c1, red));
  float ni2 = sqrtf(block_sum(c2, red));
  float s_global = expf(logit_scale[0]) * dc / (fmaxf(nt2, 1e-8f) * fmaxf(ni2, 1e-8f));

  if (tid == 0) {
    float s3[3] = { s_token[b], s_phrase, s_global };
    float h1[16];
    for (int j = 0; j < 16; ++j) {
      float a = f1b[j];
      for (int i2 = 0; i2 < 3; ++i2) a += s3[i2] * f1w[i2 * 16 + j];
      h1[j] = 0.5f * a * (1.0f + erff(a * 0.70710678118654752f));
    }
    for (int j = 0; j < 3; ++j) {
      float a = f2b[j];
      for (int i2 = 0; i2 < 16; ++i2) a += h1[i2] * f2w[i2 * 3 + j];
      sres[j] = 1.0f / (1.0f + expf(-a));
    }
  }
  __syncthreads();
  const float w0 = sres[0], w1 = sres[1], w2 = sres[2];

  for (int j = tid; j < 384; j += 256) {
    const float a = w0 * Xc[(size_t)b * 384 + j] +
                    w1 * Xc[(size_t)(32 + b) * 384 + j] +
                    w2 * Xc[(size_t)(64 + b) * 384 + j] + c1b[j];
    hid[j] = fmaxf(a, 0.0f);
  }
  __syncthreads();

  float p0 = 0.f, p1 = 0.f;
  for (int k2 = tid; k2 < 384; k2 += 256) {
    p0 += hid[k2] * c2w[k2 * 2 + 0];
    p1 += hid[k2] * c2w[k2 * 2 + 1];
  }
  p0 = block_sum(p0, red);
  p1 = block_sum(p1, red);
  if (tid == 0) {
    out[b * 2 + 0] = p0 + c2b[0];
    out[b * 2 + 1] = p1 + c2b[1];
  }
}

// ---------------- launch ----------------
extern "C" void kernel_launch(void* const* d_in, const int* in_sizes, int n_in,
                              void* d_out, int out_size, void* d_ws, size_t ws_size,
                              hipStream_t stream) {
  const float* text   = (const float*)d_in[0];
  const float* img    = (const float*)d_in[1];
  const float* clip_t = (const float*)d_in[2];
  const float* clip_i = (const float*)d_in[3];
  const float* lscale = (const float*)d_in[4];
  const float* wq = (const float*)d_in[5];
  const float* bq = (const float*)d_in[6];
  const float* wk = (const float*)d_in[7];
  const float* bk = (const float*)d_in[8];
  const float* wv = (const float*)d_in[9];
  const float* bv = (const float*)d_in[10];
  const float* wo = (const float*)d_in[11];
  const float* bo = (const float*)d_in[12];
  const float* Wt = (const float*)d_in[13];
  const float* at = (const float*)d_in[14];
  const float* Wi = (const float*)d_in[15];
  const float* ai = (const float*)d_in[16];
  const float* Wp = (const float*)d_in[17];
  const float* bp = (const float*)d_in[18];
  const float* f1w = (const float*)d_in[19];
  const float* f1b = (const float*)d_in[20];
  const float* f2w = (const float*)d_in[21];
  const float* f2b = (const float*)d_in[22];
  const float* c1w = (const float*)d_in[23];
  const float* c1b = (const float*)d_in[24];
  const float* c2w = (const float*)d_in[25];
  const float* c2b = (const float*)d_in[26];
  const int* text_adj  = (const int*)d_in[27];
  const int* image_adj = (const int*)d_in[28];
  float* out = (float*)d_out;

  const size_t nTD = (size_t)B * T * D;   // 1,572,864
  const size_t nPD = (size_t)B * P * D;   // 4,816,896
  const size_t nWW = (size_t)D * D;       // 589,824

  // ---- workspace layout (no aliasing) ----
  float* fbuf = (float*)d_ws;
  size_t o = 0;
  float* upd0    = fbuf + o; o += nTD;     // wo GEMM split-K partial 0 (with bias)
  float* upd1    = fbuf + o; o += nTD;     // partial 1
  float* ftok    = fbuf + o; o += (size_t)B * D;
  float* stok    = fbuf + o; o += 32;
  float* tgf     = fbuf + o; o += (size_t)B * D;
  float* igf     = fbuf + o; o += (size_t)B * D;
  float* fglob   = fbuf + o; o += (size_t)B * D;
  float* bcat_t  = fbuf + o; o += 1536;
  float* bcat_i3 = fbuf + o; o += 2304;
  float* sd      = fbuf + o; o += (size_t)384 * 392;
  float* Xc      = fbuf + o; o += (size_t)96 * 384;
  unsigned short* sbuf = (unsigned short*)(fbuf + o);
  size_t so = 0;
  unsigned short* kvw_bf    = sbuf + so; so += 3 * nPD;  // [B*P][2304] bf16: k|v|Wh_i
  unsigned short* qa_bf     = sbuf + so; so += 2 * nTD;  // [B*T][1536] bf16: q|Wh_t
  unsigned short* text_bf   = sbuf + so; so += nTD;
  unsigned short* img_bf    = sbuf + so; so += nPD;
  unsigned short* att_bf    = sbuf + so; so += nTD;
  unsigned short* wcat_txt  = sbuf + so; so += 2 * nWW;  // wq^T | Wt^T
  unsigned short* wcat_img3 = sbuf + so; so += 3 * nWW;  // wk^T | wv^T | Wi^T
  unsigned short* wo_t      = sbuf + so; so += nWW;
  unsigned short* S         = sbuf + so; so += (size_t)384 * 196 * 224;

  // ---- weight casts + biases + activation casts ----
  WPack wp;
  wp.src[0] = wq; wp.dst[0] = wcat_txt;
  wp.src[1] = Wt; wp.dst[1] = wcat_txt + nWW;
  wp.src[2] = wk; wp.dst[2] = wcat_img3;
  wp.src[3] = wv; wp.dst[3] = wcat_img3 + nWW;
  wp.src[4] = Wi; wp.dst[4] = wcat_img3 + 2 * nWW;
  wp.src[5] = wo; wp.dst[5] = wo_t;
  cast_transpose6<<<dim3(D / 32, D / 32, 6), 256, 0, stream>>>(wp, D, D);
  build_bias<<<12, 256, 0, stream>>>(bq, bk, bv, bcat_t, bcat_i3, stok);
  {
    const int n40 = (int)(nTD / 4), n41 = (int)(nPD / 4);
    cast_rows2<<<(n40 + n41 + 255) / 256, 256, 0, stream>>>(text, text_bf, n40, img, img_bf, n41);
  }

  const int MT = B * T;   // 2048
  const int MP = B * P;   // 6272

  // ---- fused projections (bf16 C output): one dual launch ----
  GemmJob jimg;  // kvw_bf = img @ [wk|wv|Wi] + [bk,bv,0]
  jimg.A = img_bf; jimg.Bt = wcat_img3; jimg.bias = bcat_i3; jimg.C = kvw_bf;
  jimg.N = 2304; jimg.K = D; jimg.lda = D; jimg.ldb = D; jimg.colTiles = 2304 / 128;
  GemmJob jtxt;  // qa_bf = text @ [wq|Wt] + [bq,0]
  jtxt.A = text_bf; jtxt.Bt = wcat_txt; jtxt.bias = bcat_t; jtxt.C = qa_bf;
  jtxt.N = 1536; jtxt.K = D; jtxt.lda = D; jtxt.ldb = D; jtxt.colTiles = 1536 / 128;
  const int splitBlocks = (2304 / 128) * (MP / 128);                // 882
  const int totalBlocks = splitBlocks + (1536 / 128) * (MT / 128);  // 882 + 192
  gemm_mfma_dual_bf16<<<totalBlocks, 256, 0, stream>>>(jimg, jtxt, splitBlocks);

  fglob_kernel<<<dim3(12, B), 256, 0, stream>>>(clip_t, Wp, bp, fglob);

  attn_mfma<<<dim3(H, B), 256, 0, stream>>>(qa_bf, kvw_bf, att_bf);

  // ---- wo GEMM split-K x2 in one dual launch (192 blocks) ----
  GemmJob jwo0;  // upd0 = att[:, :384] @ wo_t[:, :384]^T + bo
  jwo0.A = att_bf; jwo0.Bt = wo_t; jwo0.bias = bo; jwo0.C = upd0;
  jwo0.N = D; jwo0.K = 384; jwo0.lda = D; jwo0.ldb = D; jwo0.colTiles = D / 128;
  GemmJob jwo1;  // upd1 = att[:, 384:] @ wo_t[:, 384:]^T
  jwo1.A = att_bf + 384; jwo1.Bt = wo_t + 384; jwo1.bias = nullptr; jwo1.C = upd1;
  jwo1.N = D; jwo1.K = 384; jwo1.lda = D; jwo1.ldb = D; jwo1.colTiles = D / 128;
  const int woHalf = (D / 128) * (MT / 128);  // 96
  gemm_mfma_dual_f32<<<2 * woHalf, 256, 0, stream>>>(jwo0, jwo1, woHalf);

  token_kernel<<<dim3(12, B), 256, 0, stream>>>(upd0, upd1, img, ftok, stok);
  text_gat_mfma<<<dim3(H, B), 256, 0, stream>>>(qa_bf + 768, 1536, text_adj, at, tgf);

  // ---- image GAT: 3-stage pipeline on whi_bf = kvw_bf cols 1536.. (stride 2304) ----
  const unsigned short* whi_bf = kvw_bf + 1536;
  sd_kernel<<<MP * 12 / 4, 256, 0, stream>>>(whi_bf, 2304, ai, sd);
  score_kernel<<<dim3(49, H, B), 256, 0, stream>>>(sd, image_adj, S);
  image_gat_mfma<<<dim3(H, B), 256, 0, stream>>>(whi_bf, 2304, S, igf);

  xc1_kernel<<<dim3(6, 96), 256, 0, stream>>>(ftok, tgf, fglob, c1w, Xc);
  final_kernel<<<B, 256, 0, stream>>>(tgf, igf, clip_t, clip_i, lscale, stok, Xc,
                                      f1w, f1b, f2w, f2b, c1b, c2w, c2b, out);
}